// Round 2
// baseline (269.119 us; speedup 1.0000x reference)
//
#include <hip/hip_runtime.h>
#include <hip/hip_bf16.h>

#define NB 4
#define CC 512
#define TT 4096
#define C3 1536
#define CQK 1024
#define NTC (NB*TT*CC)   // 8388608 elems per [N,T,C] tensor

typedef __attribute__((ext_vector_type(4))) float f32x4;
typedef __attribute__((ext_vector_type(8))) short short8;
typedef unsigned short ushort;

__device__ __forceinline__ ushort f2bf(float f){
    union { float f; unsigned u; } x; x.f = f;
    unsigned r = x.u + 0x7fffu + ((x.u >> 16) & 1u);   // RNE
    return (ushort)(r >> 16);
}

// async global->LDS, 16B per lane; LDS dest = wave-uniform base + lane*16
__device__ __forceinline__ void gload16(const void* g, void* l){
    __builtin_amdgcn_global_load_lds((const __attribute__((address_space(1))) void*)g,
                                     (__attribute__((address_space(3))) void*)l,
                                     16, 0, 0);
}

// ---------------- K0a: convert weights fp32 -> bf16 ----------------
__global__ __launch_bounds__(256) void cvt_w(const float* __restrict__ Wi,
                                             const float* __restrict__ Wo,
                                             ushort* __restrict__ Wb,
                                             ushort* __restrict__ Wob){
    int t = blockIdx.x * 256 + threadIdx.x;   // 262144 threads total
    const float* src; ushort* dst; int idx;
    if (t < 196608){ src = Wi; dst = Wb;  idx = t; }
    else           { src = Wo; dst = Wob; idx = t - 196608; }
    f32x4 v = *((const f32x4*)src + idx);
    ushort4 o;
    o.x = f2bf(v[0]); o.y = f2bf(v[1]); o.z = f2bf(v[2]); o.w = f2bf(v[3]);
    *((ushort4*)dst + idx) = o;
}

// ---------------- K0b: transpose+cvt q/k/v [N,C,T] fp32 -> [N,T,C] bf16 ----------------
__global__ __launch_bounds__(256) void transpose_cvt(const float* __restrict__ q,
                                                     const float* __restrict__ k,
                                                     const float* __restrict__ v,
                                                     ushort* __restrict__ XT){
    __shared__ float sT[64][65];   // [t][c], padded
    int b = blockIdx.x;
    int tch = b % 64;  b /= 64;
    int cch = b % 8;   b /= 8;
    int n   = b % 4;   b /= 4;
    int which = b;     // 0=q 1=k 2=v
    const float* src = (which == 0) ? q : (which == 1) ? k : v;
    const float* base = src + (size_t)n*CC*TT + (size_t)(cch*64)*TT + (size_t)tch*64;
    for (int i = 0; i < 4; ++i){
        int f = i*256 + threadIdx.x;
        int t4 = f & 15, c = f >> 4;
        f32x4 val = *(const f32x4*)(base + (size_t)c*TT + t4*4);
        for (int j = 0; j < 4; ++j) sT[t4*4 + j][c] = val[j];
    }
    __syncthreads();
    ushort* dst = XT + (size_t)which*NTC + ((size_t)n*TT + (size_t)tch*64)*CC + cch*64;
    for (int i = 0; i < 4; ++i){
        int f = i*256 + threadIdx.x;
        int c4 = f & 15, t = f >> 4;
        ushort4 o;
        o.x = f2bf(sT[t][c4*4+0]); o.y = f2bf(sT[t][c4*4+1]);
        o.z = f2bf(sT[t][c4*4+2]); o.w = f2bf(sT[t][c4*4+3]);
        *(ushort4*)(dst + (size_t)t*CC + c4*4) = o;
    }
}

// ---------------- K1: packed QKV projection GEMM (m97-style staging) ----------------
// Q,K -> P[m][1024]; V -> Vt[n][h][d][t] (transposed for attention's PV matmul)
// 1D grid 1536 blocks; bid&7 ~ XCD so the 12 co-tiles of one m-tile share an XCD's L2
__global__ __launch_bounds__(256) void proj_gemm(const ushort* __restrict__ XT,
                                                 const ushort* __restrict__ Wb,
                                                 const float* __restrict__ b_in,
                                                 ushort* __restrict__ P,
                                                 ushort* __restrict__ Vt){
    __shared__ ushort sA[128*64];   // swizzled: 16B block (m,k8) holds global kk = k8^(m&7)
    __shared__ ushort sB[128*64];
    const int tid = threadIdx.x;
    const int bid = blockIdx.x;
    const int mtile  = ((bid & 7) << 4) | ((bid >> 3) & 15);
    const int cotile = bid >> 7;               // 0..11
    const int co0 = cotile * 128;
    const int m0  = mtile * 128;
    const int which = co0 >> 9;                // 0:q 1:k 2:v
    const ushort* Abase = XT + (size_t)which*NTC + (size_t)m0*CC;
    const ushort* Bbase = Wb + (size_t)co0*CC;
    const int w = tid >> 6, lane = tid & 63;
    const int wr = w >> 1, wc = w & 1;
    const int l15 = lane & 15, quad = lane >> 4;

    const ushort* gA[4]; const ushort* gB[4];
    ushort* lA[4]; ushort* lB[4];
    for (int i = 0; i < 4; ++i){
        int slot = i*256 + tid;
        int m = slot >> 3, k8 = slot & 7, kk = k8 ^ (m & 7);
        gA[i] = Abase + (size_t)m*CC + kk*8;
        gB[i] = Bbase + (size_t)m*CC + kk*8;
        int lbase = (i*256 + (tid & ~63)) * 8;
        lA[i] = sA + lbase;  lB[i] = sB + lbase;
    }

    f32x4 acc[4][4] = {};
    for (int kb = 0; kb < 8; ++kb){
        __syncthreads();
        for (int i = 0; i < 4; ++i){
            gload16(gA[i] + kb*64, lA[i]);
            gload16(gB[i] + kb*64, lB[i]);
        }
        __syncthreads();
        for (int ks = 0; ks < 2; ++ks){
            short8 aF[4], bF[4];
            for (int mi = 0; mi < 4; ++mi){
                int m = wr*64 + mi*16 + l15;
                aF[mi] = *(const short8*)&sA[(m*8 + ((ks*4 + quad) ^ (m & 7)))*8];
            }
            for (int ni = 0; ni < 4; ++ni){
                int m = wc*64 + ni*16 + l15;
                bF[ni] = *(const short8*)&sB[(m*8 + ((ks*4 + quad) ^ (m & 7)))*8];
            }
            for (int mi = 0; mi < 4; ++mi)
                for (int ni = 0; ni < 4; ++ni)
                    acc[mi][ni] = __builtin_amdgcn_mfma_f32_16x16x32_bf16(
                        aF[mi], bF[ni], acc[mi][ni], 0, 0, 0);
        }
    }

    float bj[4];
    for (int ni = 0; ni < 4; ++ni) bj[ni] = b_in[co0 + wc*64 + ni*16 + l15];
    if (which < 2){
        for (int mi = 0; mi < 4; ++mi){
            int m = m0 + wr*64 + mi*16 + quad*4;
            for (int ni = 0; ni < 4; ++ni){
                int col = (co0 & 511) + wc*64 + ni*16 + l15;
                ushort* dst = P + (size_t)m*CQK + which*512 + col;
                for (int r = 0; r < 4; ++r)
                    dst[(size_t)r*CQK] = f2bf(acc[mi][ni][r] + bj[ni]);
            }
        }
    } else {
        for (int mi = 0; mi < 4; ++mi){
            int m = m0 + wr*64 + mi*16 + quad*4;
            int n = m >> 12, t = m & 4095;
            for (int ni = 0; ni < 4; ++ni){
                int col = (co0 & 511) + wc*64 + ni*16 + l15;
                int h = col >> 6, d = col & 63;
                ushort4 o4;
                o4.x = f2bf(acc[mi][ni][0] + bj[ni]);
                o4.y = f2bf(acc[mi][ni][1] + bj[ni]);
                o4.z = f2bf(acc[mi][ni][2] + bj[ni]);
                o4.w = f2bf(acc[mi][ni][3] + bj[ni]);
                *(ushort4*)&Vt[(((size_t)n*8 + h)*64 + d)*TT + t] = o4;
            }
        }
    }
}

// ---------------- K2: per-(n,chunk,head) attention ----------------
__global__ __launch_bounds__(256) void attn_kernel(const ushort* __restrict__ P,
                                                   const ushort* __restrict__ Vt,
                                                   const float* __restrict__ masks,
                                                   ushort* __restrict__ ctx){
    __shared__ ushort sQ[64*64], sK[64*64], sV[64*64];   // swizzled
    __shared__ ushort sP[64][72];
    int bid = blockIdx.x;
    int h = bid & 7, ch = (bid >> 3) & 63, n = bid >> 9;
    const int tid = threadIdx.x, lane = tid & 63, w = tid >> 6;
    const int l15 = lane & 15, quad = lane >> 4;
    const size_t rowbase = (size_t)n*TT + (size_t)ch*64;
    for (int i = 0; i < 2; ++i){
        int slot = i*256 + tid;
        int r = slot >> 3, k8 = slot & 7, kk = k8 ^ (r & 7);
        int lbase = (i*256 + (tid & ~63)) * 8;
        const ushort* gq = P + (rowbase + r)*CQK + h*64 + kk*8;
        gload16(gq,        sQ + lbase);
        gload16(gq + 512,  sK + lbase);
        const ushort* gv = Vt + (((size_t)n*8 + h)*64 + r)*TT + ch*64 + kk*8;
        gload16(gv,        sV + lbase);
    }
    __syncthreads();
    const int m0w = w*16;
    // S = Q K^T (wave's 16 rows x 64 cols)
    short8 aQ[2]; f32x4 accS[4] = {};
    for (int ks = 0; ks < 2; ++ks){
        int m = m0w + l15;
        aQ[ks] = *(const short8*)&sQ[(m*8 + ((ks*4 + quad) ^ (m & 7)))*8];
    }
    for (int ni = 0; ni < 4; ++ni)
        for (int ks = 0; ks < 2; ++ks){
            int m = ni*16 + l15;
            short8 bK = *(const short8*)&sK[(m*8 + ((ks*4 + quad) ^ (m & 7)))*8];
            accS[ni] = __builtin_amdgcn_mfma_f32_16x16x32_bf16(aQ[ks], bK, accS[ni], 0,0,0);
        }
    // softmax over 64 key cols
    float madd[4];
    for (int ni = 0; ni < 4; ++ni){
        float mv = masks[(size_t)n*TT + ch*64 + ni*16 + l15];
        madd[ni] = (mv > 0.f) ? 0.f : -1e9f;
    }
    float s[4][4];
    for (int ni = 0; ni < 4; ++ni)
        for (int r = 0; r < 4; ++r) s[ni][r] = accS[ni][r]*0.125f + madd[ni];
    float ex[4][4];
    for (int r = 0; r < 4; ++r){
        float m1 = fmaxf(fmaxf(s[0][r], s[1][r]), fmaxf(s[2][r], s[3][r]));
        for (int d = 1; d < 16; d <<= 1) m1 = fmaxf(m1, __shfl_xor(m1, d));
        float a = 0.f;
        for (int ni = 0; ni < 4; ++ni){ float e = __expf(s[ni][r] - m1); ex[ni][r] = e; a += e; }
        for (int d = 1; d < 16; d <<= 1) a += __shfl_xor(a, d);
        float rs = 1.0f / a;
        for (int ni = 0; ni < 4; ++ni)
            sP[m0w + quad*4 + r][ni*16 + l15] = f2bf(ex[ni][r] * rs);
    }
    // O = P V^T-staged  (sP rows are wave-private; same-wave LDS dep handled by lgkmcnt)
    short8 aP[2]; f32x4 accO[4] = {};
    for (int ks = 0; ks < 2; ++ks)
        aP[ks] = *(const short8*)&sP[m0w + l15][ks*32 + quad*8];
    for (int ni = 0; ni < 4; ++ni)
        for (int ks = 0; ks < 2; ++ks){
            int m = ni*16 + l15;
            short8 bV = *(const short8*)&sV[(m*8 + ((ks*4 + quad) ^ (m & 7)))*8];
            accO[ni] = __builtin_amdgcn_mfma_f32_16x16x32_bf16(aP[ks], bV, accO[ni], 0,0,0);
        }
    for (int ni = 0; ni < 4; ++ni)
        for (int r = 0; r < 4; ++r){
            size_t row = rowbase + m0w + quad*4 + r;
            ctx[row*CC + h*64 + ni*16 + l15] = f2bf(accO[ni][r]);
        }
}

// ---------------- K3: out-projection + bias + mask + residual, transposed store ----------------
__global__ __launch_bounds__(256) void out_gemm(const ushort* __restrict__ ctx,
                                                const ushort* __restrict__ Wob,
                                                const float* __restrict__ b_out,
                                                const float* __restrict__ x,
                                                const float* __restrict__ masks,
                                                float* __restrict__ out){
    __shared__ ushort sA[128*64];
    __shared__ ushort sB[128*64];
    const int tid = threadIdx.x;
    const int bid = blockIdx.x;
    const int mtile  = ((bid & 7) << 4) | ((bid >> 3) & 15);
    const int cotile = bid >> 7;               // 0..3
    const int co0 = cotile * 128;
    const int m0  = mtile * 128;
    const int n = m0 >> 12, t0 = m0 & 4095;
    const ushort* Abase = ctx + (size_t)m0*CC;
    const ushort* Bbase = Wob + (size_t)co0*CC;
    const int w = tid >> 6, lane = tid & 63;
    const int wr = w >> 1, wc = w & 1;
    const int l15 = lane & 15, quad = lane >> 4;

    const ushort* gA[4]; const ushort* gB[4];
    ushort* lA[4]; ushort* lB[4];
    for (int i = 0; i < 4; ++i){
        int slot = i*256 + tid;
        int m = slot >> 3, k8 = slot & 7, kk = k8 ^ (m & 7);
        gA[i] = Abase + (size_t)m*CC + kk*8;
        gB[i] = Bbase + (size_t)m*CC + kk*8;
        int lbase = (i*256 + (tid & ~63)) * 8;
        lA[i] = sA + lbase;  lB[i] = sB + lbase;
    }

    f32x4 acc[4][4] = {};
    for (int kb = 0; kb < 8; ++kb){
        __syncthreads();
        for (int i = 0; i < 4; ++i){
            gload16(gA[i] + kb*64, lA[i]);
            gload16(gB[i] + kb*64, lB[i]);
        }
        __syncthreads();
        for (int ks = 0; ks < 2; ++ks){
            short8 aF[4], bF[4];
            for (int mi = 0; mi < 4; ++mi){
                int m = wr*64 + mi*16 + l15;
                aF[mi] = *(const short8*)&sA[(m*8 + ((ks*4 + quad) ^ (m & 7)))*8];
            }
            for (int ni = 0; ni < 4; ++ni){
                int m = wc*64 + ni*16 + l15;
                bF[ni] = *(const short8*)&sB[(m*8 + ((ks*4 + quad) ^ (m & 7)))*8];
            }
            for (int mi = 0; mi < 4; ++mi)
                for (int ni = 0; ni < 4; ++ni)
                    acc[mi][ni] = __builtin_amdgcn_mfma_f32_16x16x32_bf16(
                        aF[mi], bF[ni], acc[mi][ni], 0, 0, 0);
        }
    }
    float bo[4];
    for (int ni = 0; ni < 4; ++ni) bo[ni] = b_out[co0 + wc*64 + ni*16 + l15];
    for (int mi = 0; mi < 4; ++mi){
        int t = t0 + wr*64 + mi*16 + quad*4;
        f32x4 mk = *(const f32x4*)(masks + (size_t)n*TT + t);
        for (int ni = 0; ni < 4; ++ni){
            int co = co0 + wc*64 + ni*16 + l15;
            const f32x4 xv = *(const f32x4*)(x + ((size_t)n*CC + co)*TT + t);
            f32x4 o;
            for (int r = 0; r < 4; ++r)
                o[r] = (acc[mi][ni][r] + bo[ni]) * mk[r] + xv[r];
            *(f32x4*)(out + ((size_t)n*CC + co)*TT + t) = o;
        }
    }
}

// ---------------- K4: InstanceNorm over T per (n,c), in place ----------------
__global__ __launch_bounds__(256) void inorm(float* __restrict__ out){
    __shared__ float sS[4], sQ2[4];
    float* row = out + (size_t)blockIdx.x * TT;
    f32x4 vbuf[4];
    float s = 0.f, ss = 0.f;
    for (int i = 0; i < 4; ++i){
        f32x4 vv = *(const f32x4*)(row + (size_t)(i*256 + threadIdx.x)*4);
        vbuf[i] = vv;
        for (int r = 0; r < 4; ++r){ s += vv[r]; ss += vv[r]*vv[r]; }
    }
    for (int d = 1; d < 64; d <<= 1){ s += __shfl_xor(s, d); ss += __shfl_xor(ss, d); }
    int w = threadIdx.x >> 6;
    if ((threadIdx.x & 63) == 0){ sS[w] = s; sQ2[w] = ss; }
    __syncthreads();
    s  = sS[0] + sS[1] + sS[2] + sS[3];
    ss = sQ2[0] + sQ2[1] + sQ2[2] + sQ2[3];
    float mean = s * (1.0f/TT);
    float var  = ss * (1.0f/TT) - mean*mean;
    float rstd = rsqrtf(var + 1e-5f);
    for (int i = 0; i < 4; ++i){
        f32x4 vv = vbuf[i], o;
        for (int r = 0; r < 4; ++r) o[r] = (vv[r] - mean) * rstd;
        *(f32x4*)(row + (size_t)(i*256 + threadIdx.x)*4) = o;
    }
}

extern "C" void kernel_launch(void* const* d_in, const int* in_sizes, int n_in,
                              void* d_out, int out_size, void* d_ws, size_t ws_size,
                              hipStream_t stream) {
    const float* x     = (const float*)d_in[0];
    const float* q     = (const float*)d_in[1];
    const float* k     = (const float*)d_in[2];
    const float* v     = (const float*)d_in[3];
    const float* masks = (const float*)d_in[4];
    const float* W_in  = (const float*)d_in[5];
    const float* b_in  = (const float*)d_in[6];
    const float* W_out = (const float*)d_in[7];
    const float* b_out = (const float*)d_in[8];
    float* out = (float*)d_out;

    ushort* ws  = (ushort*)d_ws;
    ushort* XT  = ws;                           // 3*NTC bf16 (q,k,v transposed)
    ushort* Wb  = ws + (size_t)3*NTC;           // 786432
    ushort* Wob = Wb + 786432;                  // 262144
    ushort* P   = Wob + 262144;                 // NB*TT*CQK = 16777216 (Q,K projected)
    ushort* Vt  = P + (size_t)NB*TT*CQK;        // 8388608  (V projected, transposed)
    ushort* ctx = ws;                           // aliases XT (free after proj_gemm)

    cvt_w<<<1024, 256, 0, stream>>>(W_in, W_out, Wb, Wob);
    transpose_cvt<<<6144, 256, 0, stream>>>(q, k, v, XT);
    proj_gemm<<<1536, 256, 0, stream>>>(XT, Wb, b_in, P, Vt);
    attn_kernel<<<2048, 256, 0, stream>>>(P, Vt, masks, ctx);
    out_gemm<<<512, 256, 0, stream>>>(ctx, Wob, b_out, x, masks, out);
    inorm<<<2048, 256, 0, stream>>>(out);
}

// Round 3
// 261.364 us; speedup vs baseline: 1.0297x; 1.0297x over previous
//
#include <hip/hip_runtime.h>
#include <hip/hip_bf16.h>

#define NB 4
#define CC 512
#define TT 4096
#define C3 1536
#define CQK 1024
#define NTC (NB*TT*CC)   // 8388608 elems per [N,T,C] tensor

typedef __attribute__((ext_vector_type(4))) float f32x4;
typedef __attribute__((ext_vector_type(8))) short short8;
typedef unsigned short ushort;

__device__ __forceinline__ ushort f2bf(float f){
    union { float f; unsigned u; } x; x.f = f;
    unsigned r = x.u + 0x7fffu + ((x.u >> 16) & 1u);   // RNE
    return (ushort)(r >> 16);
}

__device__ __forceinline__ void gload16(const void* g, void* l){
    __builtin_amdgcn_global_load_lds((const __attribute__((address_space(1))) void*)g,
                                     (__attribute__((address_space(3))) void*)l,
                                     16, 0, 0);
}

// ---------------- K0: prep = weight cvt + q/k/v transpose+cvt ----------------
// blocks 0..1535: transpose 64c x 256t tile (4 sub-tiles, register-pipelined)
// blocks 1536..1791: weight fp32->bf16
__global__ __launch_bounds__(256) void prep(const float* __restrict__ q,
                                            const float* __restrict__ k,
                                            const float* __restrict__ v,
                                            const float* __restrict__ Wi,
                                            const float* __restrict__ Wo,
                                            ushort* __restrict__ XT,
                                            ushort* __restrict__ Wb,
                                            ushort* __restrict__ Wob){
    __shared__ float sT[64][65];   // [t][c], padded
    const int tid = threadIdx.x;
    int b = blockIdx.x;
    if (b >= 1536){
        int idx0 = (b - 1536) * 1024 + tid;
        for (int i = 0; i < 4; ++i){
            int idx = idx0 + i*256;
            const float* src; ushort* dst; int j;
            if (idx < 196608){ src = Wi; dst = Wb;  j = idx; }
            else             { src = Wo; dst = Wob; j = idx - 196608; }
            f32x4 vv = *((const f32x4*)src + j);
            ushort4 o;
            o.x = f2bf(vv[0]); o.y = f2bf(vv[1]); o.z = f2bf(vv[2]); o.w = f2bf(vv[3]);
            *((ushort4*)dst + j) = o;
        }
        return;
    }
    int tq = b & 15;  b >>= 4;     // t-chunk of 256
    int cch = b & 7;  b >>= 3;     // c-chunk of 64
    int n   = b & 3;  b >>= 2;
    int which = b;                 // 0=q 1=k 2=v
    const float* src = (which == 0) ? q : (which == 1) ? k : v;
    const float* base = src + (size_t)n*CC*TT + (size_t)(cch*64)*TT + (size_t)tq*256;
    ushort* dstb = XT + (size_t)which*NTC + ((size_t)n*TT + (size_t)tq*256)*CC + cch*64;

    int t4l[4], cl[4];
    for (int i = 0; i < 4; ++i){ int f = i*256 + tid; t4l[i] = f & 15; cl[i] = f >> 4; }

    f32x4 cur[4], nxt[4];
    for (int i = 0; i < 4; ++i)
        cur[i] = *(const f32x4*)(base + (size_t)cl[i]*TT + t4l[i]*4);
    #pragma unroll
    for (int s = 0; s < 4; ++s){
        if (s < 3)
            for (int i = 0; i < 4; ++i)
                nxt[i] = *(const f32x4*)(base + (size_t)cl[i]*TT + (s+1)*64 + t4l[i]*4);
        for (int i = 0; i < 4; ++i)
            for (int j = 0; j < 4; ++j) sT[t4l[i]*4 + j][cl[i]] = cur[i][j];
        __syncthreads();
        ushort* dst = dstb + (size_t)(s*64)*CC;
        for (int i = 0; i < 4; ++i){
            int f = i*256 + tid;
            int c4 = f & 15, t = f >> 4;
            ushort4 o;
            o.x = f2bf(sT[t][c4*4+0]); o.y = f2bf(sT[t][c4*4+1]);
            o.z = f2bf(sT[t][c4*4+2]); o.w = f2bf(sT[t][c4*4+3]);
            *(ushort4*)(dst + (size_t)t*CC + c4*4) = o;
        }
        __syncthreads();
        for (int i = 0; i < 4; ++i) cur[i] = nxt[i];
    }
}

// ---------------- K1: packed QKV projection GEMM (m97-style staging) ----------------
__global__ __launch_bounds__(256) void proj_gemm(const ushort* __restrict__ XT,
                                                 const ushort* __restrict__ Wb,
                                                 const float* __restrict__ b_in,
                                                 ushort* __restrict__ P,
                                                 ushort* __restrict__ Vt){
    __shared__ ushort sA[128*64];   // swizzled: 16B block (m,k8) holds global kk = k8^(m&7)
    __shared__ ushort sB[128*64];
    const int tid = threadIdx.x;
    const int bid = blockIdx.x;
    const int mtile  = ((bid & 7) << 4) | ((bid >> 3) & 15);
    const int cotile = bid >> 7;               // 0..11
    const int co0 = cotile * 128;
    const int m0  = mtile * 128;
    const int which = co0 >> 9;                // 0:q 1:k 2:v
    const ushort* Abase = XT + (size_t)which*NTC + (size_t)m0*CC;
    const ushort* Bbase = Wb + (size_t)co0*CC;
    const int w = tid >> 6, lane = tid & 63;
    const int wr = w >> 1, wc = w & 1;
    const int l15 = lane & 15, quad = lane >> 4;

    const ushort* gA[4]; const ushort* gB[4];
    ushort* lA[4]; ushort* lB[4];
    for (int i = 0; i < 4; ++i){
        int slot = i*256 + tid;
        int m = slot >> 3, k8 = slot & 7, kk = k8 ^ (m & 7);
        gA[i] = Abase + (size_t)m*CC + kk*8;
        gB[i] = Bbase + (size_t)m*CC + kk*8;
        int lbase = (i*256 + (tid & ~63)) * 8;
        lA[i] = sA + lbase;  lB[i] = sB + lbase;
    }

    f32x4 acc[4][4] = {};
    for (int kb = 0; kb < 8; ++kb){
        __syncthreads();
        for (int i = 0; i < 4; ++i){
            gload16(gA[i] + kb*64, lA[i]);
            gload16(gB[i] + kb*64, lB[i]);
        }
        __syncthreads();
        for (int ks = 0; ks < 2; ++ks){
            short8 aF[4], bF[4];
            for (int mi = 0; mi < 4; ++mi){
                int m = wr*64 + mi*16 + l15;
                aF[mi] = *(const short8*)&sA[(m*8 + ((ks*4 + quad) ^ (m & 7)))*8];
            }
            for (int ni = 0; ni < 4; ++ni){
                int m = wc*64 + ni*16 + l15;
                bF[ni] = *(const short8*)&sB[(m*8 + ((ks*4 + quad) ^ (m & 7)))*8];
            }
            for (int mi = 0; mi < 4; ++mi)
                for (int ni = 0; ni < 4; ++ni)
                    acc[mi][ni] = __builtin_amdgcn_mfma_f32_16x16x32_bf16(
                        aF[mi], bF[ni], acc[mi][ni], 0, 0, 0);
        }
    }

    float bj[4];
    for (int ni = 0; ni < 4; ++ni) bj[ni] = b_in[co0 + wc*64 + ni*16 + l15];
    if (which < 2){
        for (int mi = 0; mi < 4; ++mi){
            int m = m0 + wr*64 + mi*16 + quad*4;
            for (int ni = 0; ni < 4; ++ni){
                int col = (co0 & 511) + wc*64 + ni*16 + l15;
                ushort* dst = P + (size_t)m*CQK + which*512 + col;
                for (int r = 0; r < 4; ++r)
                    dst[(size_t)r*CQK] = f2bf(acc[mi][ni][r] + bj[ni]);
            }
        }
    } else {
        for (int mi = 0; mi < 4; ++mi){
            int m = m0 + wr*64 + mi*16 + quad*4;
            int n = m >> 12, t = m & 4095;
            for (int ni = 0; ni < 4; ++ni){
                int col = (co0 & 511) + wc*64 + ni*16 + l15;
                int h = col >> 6, d = col & 63;
                ushort4 o4;
                o4.x = f2bf(acc[mi][ni][0] + bj[ni]);
                o4.y = f2bf(acc[mi][ni][1] + bj[ni]);
                o4.z = f2bf(acc[mi][ni][2] + bj[ni]);
                o4.w = f2bf(acc[mi][ni][3] + bj[ni]);
                *(ushort4*)&Vt[(((size_t)n*8 + h)*64 + d)*TT + t] = o4;
            }
        }
    }
}

// ---------------- K2: per-(n,chunk,head) attention ----------------
__global__ __launch_bounds__(256) void attn_kernel(const ushort* __restrict__ P,
                                                   const ushort* __restrict__ Vt,
                                                   const float* __restrict__ masks,
                                                   ushort* __restrict__ ctx){
    __shared__ ushort sQ[64*64], sK[64*64], sV[64*64];   // swizzled
    __shared__ ushort sP[64][72];
    int bid = blockIdx.x;
    int h = bid & 7, ch = (bid >> 3) & 63, n = bid >> 9;
    const int tid = threadIdx.x, lane = tid & 63, w = tid >> 6;
    const int l15 = lane & 15, quad = lane >> 4;
    const size_t rowbase = (size_t)n*TT + (size_t)ch*64;
    for (int i = 0; i < 2; ++i){
        int slot = i*256 + tid;
        int r = slot >> 3, k8 = slot & 7, kk = k8 ^ (r & 7);
        int lbase = (i*256 + (tid & ~63)) * 8;
        const ushort* gq = P + (rowbase + r)*CQK + h*64 + kk*8;
        gload16(gq,        sQ + lbase);
        gload16(gq + 512,  sK + lbase);
        const ushort* gv = Vt + (((size_t)n*8 + h)*64 + r)*TT + ch*64 + kk*8;
        gload16(gv,        sV + lbase);
    }
    __syncthreads();
    const int m0w = w*16;
    short8 aQ[2]; f32x4 accS[4] = {};
    for (int ks = 0; ks < 2; ++ks){
        int m = m0w + l15;
        aQ[ks] = *(const short8*)&sQ[(m*8 + ((ks*4 + quad) ^ (m & 7)))*8];
    }
    for (int ni = 0; ni < 4; ++ni)
        for (int ks = 0; ks < 2; ++ks){
            int m = ni*16 + l15;
            short8 bK = *(const short8*)&sK[(m*8 + ((ks*4 + quad) ^ (m & 7)))*8];
            accS[ni] = __builtin_amdgcn_mfma_f32_16x16x32_bf16(aQ[ks], bK, accS[ni], 0,0,0);
        }
    float madd[4];
    for (int ni = 0; ni < 4; ++ni){
        float mv = masks[(size_t)n*TT + ch*64 + ni*16 + l15];
        madd[ni] = (mv > 0.f) ? 0.f : -1e9f;
    }
    float s[4][4];
    for (int ni = 0; ni < 4; ++ni)
        for (int r = 0; r < 4; ++r) s[ni][r] = accS[ni][r]*0.125f + madd[ni];
    float ex[4][4];
    for (int r = 0; r < 4; ++r){
        float m1 = fmaxf(fmaxf(s[0][r], s[1][r]), fmaxf(s[2][r], s[3][r]));
        for (int d = 1; d < 16; d <<= 1) m1 = fmaxf(m1, __shfl_xor(m1, d));
        float a = 0.f;
        for (int ni = 0; ni < 4; ++ni){ float e = __expf(s[ni][r] - m1); ex[ni][r] = e; a += e; }
        for (int d = 1; d < 16; d <<= 1) a += __shfl_xor(a, d);
        float rs = 1.0f / a;
        for (int ni = 0; ni < 4; ++ni)
            sP[m0w + quad*4 + r][ni*16 + l15] = f2bf(ex[ni][r] * rs);
    }
    short8 aP[2]; f32x4 accO[4] = {};
    for (int ks = 0; ks < 2; ++ks)
        aP[ks] = *(const short8*)&sP[m0w + l15][ks*32 + quad*8];
    for (int ni = 0; ni < 4; ++ni)
        for (int ks = 0; ks < 2; ++ks){
            int m = ni*16 + l15;
            short8 bV = *(const short8*)&sV[(m*8 + ((ks*4 + quad) ^ (m & 7)))*8];
            accO[ni] = __builtin_amdgcn_mfma_f32_16x16x32_bf16(aP[ks], bV, accO[ni], 0,0,0);
        }
    for (int ni = 0; ni < 4; ++ni)
        for (int r = 0; r < 4; ++r){
            size_t row = rowbase + m0w + quad*4 + r;
            ctx[row*CC + h*64 + ni*16 + l15] = f2bf(accO[ni][r]);
        }
}

// ---------------- K3: out-projection, 128m x 64co tiles ----------------
__global__ __launch_bounds__(256) void out_gemm(const ushort* __restrict__ ctx,
                                                const ushort* __restrict__ Wob,
                                                const float* __restrict__ b_out,
                                                const float* __restrict__ x,
                                                const float* __restrict__ masks,
                                                float* __restrict__ out){
    __shared__ ushort sA[128*64];
    __shared__ ushort sB[64*64];
    const int tid = threadIdx.x;
    const int bid = blockIdx.x;
    const int mtile  = ((bid & 7) << 4) | ((bid >> 3) & 15);
    const int cotile = bid >> 7;               // 0..7
    const int co0 = cotile * 64;
    const int m0  = mtile * 128;
    const int n = m0 >> 12, t0 = m0 & 4095;
    const ushort* Abase = ctx + (size_t)m0*CC;
    const ushort* Bbase = Wob + (size_t)co0*CC;
    const int w = tid >> 6, lane = tid & 63;
    const int wr = w >> 1, wc = w & 1;
    const int l15 = lane & 15, quad = lane >> 4;

    const ushort* gA[4]; ushort* lA[4];
    const ushort* gB[2]; ushort* lB[2];
    for (int i = 0; i < 4; ++i){
        int slot = i*256 + tid;
        int m = slot >> 3, k8 = slot & 7, kk = k8 ^ (m & 7);
        gA[i] = Abase + (size_t)m*CC + kk*8;
        lA[i] = sA + (i*256 + (tid & ~63)) * 8;
    }
    for (int i = 0; i < 2; ++i){
        int slot = i*256 + tid;
        int m = slot >> 3, k8 = slot & 7, kk = k8 ^ (m & 7);
        gB[i] = Bbase + (size_t)m*CC + kk*8;
        lB[i] = sB + (i*256 + (tid & ~63)) * 8;
    }

    f32x4 acc[4][2] = {};
    for (int kb = 0; kb < 8; ++kb){
        __syncthreads();
        for (int i = 0; i < 4; ++i) gload16(gA[i] + kb*64, lA[i]);
        for (int i = 0; i < 2; ++i) gload16(gB[i] + kb*64, lB[i]);
        __syncthreads();
        for (int ks = 0; ks < 2; ++ks){
            short8 aF[4], bF[2];
            for (int mi = 0; mi < 4; ++mi){
                int m = wr*64 + mi*16 + l15;
                aF[mi] = *(const short8*)&sA[(m*8 + ((ks*4 + quad) ^ (m & 7)))*8];
            }
            for (int ni = 0; ni < 2; ++ni){
                int m = wc*32 + ni*16 + l15;
                bF[ni] = *(const short8*)&sB[(m*8 + ((ks*4 + quad) ^ (m & 7)))*8];
            }
            for (int mi = 0; mi < 4; ++mi)
                for (int ni = 0; ni < 2; ++ni)
                    acc[mi][ni] = __builtin_amdgcn_mfma_f32_16x16x32_bf16(
                        aF[mi], bF[ni], acc[mi][ni], 0, 0, 0);
        }
    }
    float bo[2];
    for (int ni = 0; ni < 2; ++ni) bo[ni] = b_out[co0 + wc*32 + ni*16 + l15];
    for (int mi = 0; mi < 4; ++mi){
        int t = t0 + wr*64 + mi*16 + quad*4;
        f32x4 mk = *(const f32x4*)(masks + (size_t)n*TT + t);
        for (int ni = 0; ni < 2; ++ni){
            int co = co0 + wc*32 + ni*16 + l15;
            const f32x4 xv = *(const f32x4*)(x + ((size_t)n*CC + co)*TT + t);
            f32x4 o;
            for (int r = 0; r < 4; ++r)
                o[r] = (acc[mi][ni][r] + bo[ni]) * mk[r] + xv[r];
            *(f32x4*)(out + ((size_t)n*CC + co)*TT + t) = o;
        }
    }
}

// ---------------- K4: InstanceNorm over T per (n,c), in place ----------------
__global__ __launch_bounds__(256) void inorm(float* __restrict__ out){
    __shared__ float sS[4], sQ2[4];
    float* row = out + (size_t)blockIdx.x * TT;
    f32x4 vbuf[4];
    float s = 0.f, ss = 0.f;
    for (int i = 0; i < 4; ++i){
        f32x4 vv = *(const f32x4*)(row + (size_t)(i*256 + threadIdx.x)*4);
        vbuf[i] = vv;
        for (int r = 0; r < 4; ++r){ s += vv[r]; ss += vv[r]*vv[r]; }
    }
    for (int d = 1; d < 64; d <<= 1){ s += __shfl_xor(s, d); ss += __shfl_xor(ss, d); }
    int w = threadIdx.x >> 6;
    if ((threadIdx.x & 63) == 0){ sS[w] = s; sQ2[w] = ss; }
    __syncthreads();
    s  = sS[0] + sS[1] + sS[2] + sS[3];
    ss = sQ2[0] + sQ2[1] + sQ2[2] + sQ2[3];
    float mean = s * (1.0f/TT);
    float var  = ss * (1.0f/TT) - mean*mean;
    float rstd = rsqrtf(var + 1e-5f);
    for (int i = 0; i < 4; ++i){
        f32x4 vv = vbuf[i], o;
        for (int r = 0; r < 4; ++r) o[r] = (vv[r] - mean) * rstd;
        *(f32x4*)(row + (size_t)(i*256 + threadIdx.x)*4) = o;
    }
}

extern "C" void kernel_launch(void* const* d_in, const int* in_sizes, int n_in,
                              void* d_out, int out_size, void* d_ws, size_t ws_size,
                              hipStream_t stream) {
    const float* x     = (const float*)d_in[0];
    const float* q     = (const float*)d_in[1];
    const float* k     = (const float*)d_in[2];
    const float* v     = (const float*)d_in[3];
    const float* masks = (const float*)d_in[4];
    const float* W_in  = (const float*)d_in[5];
    const float* b_in  = (const float*)d_in[6];
    const float* W_out = (const float*)d_in[7];
    const float* b_out = (const float*)d_in[8];
    float* out = (float*)d_out;

    ushort* ws  = (ushort*)d_ws;
    ushort* XT  = ws;                           // 3*NTC bf16 (q,k,v transposed)
    ushort* Wb  = ws + (size_t)3*NTC;           // 786432
    ushort* Wob = Wb + 786432;                  // 262144
    ushort* P   = Wob + 262144;                 // NB*TT*CQK (Q,K projected)
    ushort* Vt  = P + (size_t)NB*TT*CQK;        // NTC (V projected, transposed)
    ushort* ctx = ws;                           // aliases XT (free after proj_gemm)

    prep<<<1792, 256, 0, stream>>>(q, k, v, W_in, W_out, XT, Wb, Wob);
    proj_gemm<<<1536, 256, 0, stream>>>(XT, Wb, b_in, P, Vt);
    attn_kernel<<<2048, 256, 0, stream>>>(P, Vt, masks, ctx);
    out_gemm<<<1024, 256, 0, stream>>>(ctx, Wob, b_out, x, masks, out);
    inorm<<<2048, 256, 0, stream>>>(out);
}

// Round 4
// 260.296 us; speedup vs baseline: 1.0339x; 1.0041x over previous
//
#include <hip/hip_runtime.h>
#include <hip/hip_bf16.h>

#define NB 4
#define CC 512
#define TT 4096
#define C3 1536
#define CQK 1024
#define NTC (NB*TT*CC)   // 8388608 elems per [N,T,C] tensor

typedef __attribute__((ext_vector_type(4))) float f32x4;
typedef __attribute__((ext_vector_type(8))) short short8;
typedef unsigned short ushort;
typedef __attribute__((ext_vector_type(8))) ushort u16x8;

__device__ __forceinline__ ushort f2bf(float f){
    union { float f; unsigned u; } x; x.f = f;
    unsigned r = x.u + 0x7fffu + ((x.u >> 16) & 1u);   // RNE
    return (ushort)(r >> 16);
}

__device__ __forceinline__ ushort2 pk2bf(float a, float b){
    float2 f2; f2.x = a; f2.y = b;
    __hip_bfloat162 h = __float22bfloat162_rn(f2);     // v_cvt_pk_bf16_f32 (RNE)
    union { __hip_bfloat162 h2; ushort2 u2; } u; u.h2 = h;
    return u.u2;
}

__device__ __forceinline__ void gload16(const void* g, void* l){
    __builtin_amdgcn_global_load_lds((const __attribute__((address_space(1))) void*)g,
                                     (__attribute__((address_space(3))) void*)l,
                                     16, 0, 0);
}

// ---------------- K0: prep = q/k/v transpose+cvt (register micro-transpose) + weight cvt ----------------
// blocks 0..3071: transpose 64c x 128t tile, no LDS
// blocks 3072..3327: weight fp32->bf16
__global__ __launch_bounds__(256) void prep(const float* __restrict__ q,
                                            const float* __restrict__ k,
                                            const float* __restrict__ v,
                                            const float* __restrict__ Wi,
                                            const float* __restrict__ Wo,
                                            ushort* __restrict__ XT,
                                            ushort* __restrict__ Wb,
                                            ushort* __restrict__ Wob){
    const int tid = threadIdx.x;
    int b = blockIdx.x;
    if (b >= 3072){
        int idx0 = (b - 3072) * 1024 + tid;
        for (int i = 0; i < 4; ++i){
            int idx = idx0 + i*256;
            const float* src; ushort* dst; int j;
            if (idx < 196608){ src = Wi; dst = Wb;  j = idx; }
            else             { src = Wo; dst = Wob; j = idx - 196608; }
            f32x4 vv = *((const f32x4*)src + j);
            ushort4 o;
            *(ushort2*)&o.x = pk2bf(vv[0], vv[1]);
            *(ushort2*)&o.z = pk2bf(vv[2], vv[3]);
            *((ushort4*)dst + j) = o;
        }
        return;
    }
    int tq  = b & 31;        // t-chunk of 128
    int cch = (b >> 5) & 7;  // c-chunk of 64
    int n   = (b >> 8) & 3;
    int which = b >> 10;     // 0=q 1=k 2=v
    const float* src = (which == 0) ? q : (which == 1) ? k : v;
    const int c0   = (tid & 7) * 8;      // 8 c-rows per thread
    const int trel = (tid >> 3) * 4;     // 4 t per thread (0..124)
    const float* base = src + (size_t)n*CC*TT + (size_t)(cch*64 + c0)*TT + (size_t)tq*128 + trel;

    f32x4 cur[8];
    #pragma unroll
    for (int j = 0; j < 8; ++j)
        cur[j] = *(const f32x4*)(base + (size_t)j*TT);

    ushort* dst = XT + (size_t)which*NTC
                + ((size_t)n*TT + (size_t)tq*128 + trel)*CC + cch*64 + c0;
    #pragma unroll
    for (int tj = 0; tj < 4; ++tj){
        u16x8 o;
        #pragma unroll
        for (int j = 0; j < 8; j += 2){
            ushort2 p = pk2bf(cur[j][tj], cur[j+1][tj]);
            o[j] = p.x; o[j+1] = p.y;
        }
        *(u16x8*)(dst + (size_t)tj*CC) = o;
    }
}

// ---------------- K1: packed QKV projection GEMM (m97-style staging) ----------------
__global__ __launch_bounds__(256) void proj_gemm(const ushort* __restrict__ XT,
                                                 const ushort* __restrict__ Wb,
                                                 const float* __restrict__ b_in,
                                                 ushort* __restrict__ P,
                                                 ushort* __restrict__ Vt){
    __shared__ ushort sA[128*64];   // swizzled: 16B block (m,k8) holds global kk = k8^(m&7)
    __shared__ ushort sB[128*64];
    const int tid = threadIdx.x;
    const int bid = blockIdx.x;
    const int mtile  = ((bid & 7) << 4) | ((bid >> 3) & 15);
    const int cotile = bid >> 7;               // 0..11
    const int co0 = cotile * 128;
    const int m0  = mtile * 128;
    const int which = co0 >> 9;                // 0:q 1:k 2:v
    const ushort* Abase = XT + (size_t)which*NTC + (size_t)m0*CC;
    const ushort* Bbase = Wb + (size_t)co0*CC;
    const int w = tid >> 6, lane = tid & 63;
    const int wr = w >> 1, wc = w & 1;
    const int l15 = lane & 15, quad = lane >> 4;

    const ushort* gA[4]; const ushort* gB[4];
    ushort* lA[4]; ushort* lB[4];
    for (int i = 0; i < 4; ++i){
        int slot = i*256 + tid;
        int m = slot >> 3, k8 = slot & 7, kk = k8 ^ (m & 7);
        gA[i] = Abase + (size_t)m*CC + kk*8;
        gB[i] = Bbase + (size_t)m*CC + kk*8;
        int lbase = (i*256 + (tid & ~63)) * 8;
        lA[i] = sA + lbase;  lB[i] = sB + lbase;
    }

    f32x4 acc[4][4] = {};
    for (int kb = 0; kb < 8; ++kb){
        __syncthreads();
        for (int i = 0; i < 4; ++i){
            gload16(gA[i] + kb*64, lA[i]);
            gload16(gB[i] + kb*64, lB[i]);
        }
        __syncthreads();
        for (int ks = 0; ks < 2; ++ks){
            short8 aF[4], bF[4];
            for (int mi = 0; mi < 4; ++mi){
                int m = wr*64 + mi*16 + l15;
                aF[mi] = *(const short8*)&sA[(m*8 + ((ks*4 + quad) ^ (m & 7)))*8];
            }
            for (int ni = 0; ni < 4; ++ni){
                int m = wc*64 + ni*16 + l15;
                bF[ni] = *(const short8*)&sB[(m*8 + ((ks*4 + quad) ^ (m & 7)))*8];
            }
            for (int mi = 0; mi < 4; ++mi)
                for (int ni = 0; ni < 4; ++ni)
                    acc[mi][ni] = __builtin_amdgcn_mfma_f32_16x16x32_bf16(
                        aF[mi], bF[ni], acc[mi][ni], 0, 0, 0);
        }
    }

    float bj[4];
    for (int ni = 0; ni < 4; ++ni) bj[ni] = b_in[co0 + wc*64 + ni*16 + l15];
    if (which < 2){
        for (int mi = 0; mi < 4; ++mi){
            int m = m0 + wr*64 + mi*16 + quad*4;
            for (int ni = 0; ni < 4; ++ni){
                int col = (co0 & 511) + wc*64 + ni*16 + l15;
                ushort* dst = P + (size_t)m*CQK + which*512 + col;
                for (int r = 0; r < 4; ++r)
                    dst[(size_t)r*CQK] = f2bf(acc[mi][ni][r] + bj[ni]);
            }
        }
    } else {
        for (int mi = 0; mi < 4; ++mi){
            int m = m0 + wr*64 + mi*16 + quad*4;
            int n = m >> 12, t = m & 4095;
            for (int ni = 0; ni < 4; ++ni){
                int col = (co0 & 511) + wc*64 + ni*16 + l15;
                int h = col >> 6, d = col & 63;
                ushort4 o4;
                o4.x = f2bf(acc[mi][ni][0] + bj[ni]);
                o4.y = f2bf(acc[mi][ni][1] + bj[ni]);
                o4.z = f2bf(acc[mi][ni][2] + bj[ni]);
                o4.w = f2bf(acc[mi][ni][3] + bj[ni]);
                *(ushort4*)&Vt[(((size_t)n*8 + h)*64 + d)*TT + t] = o4;
            }
        }
    }
}

// ---------------- K2: per-(n,chunk,head) attention ----------------
__global__ __launch_bounds__(256) void attn_kernel(const ushort* __restrict__ P,
                                                   const ushort* __restrict__ Vt,
                                                   const float* __restrict__ masks,
                                                   ushort* __restrict__ ctx){
    __shared__ ushort sQ[64*64], sK[64*64], sV[64*64];   // swizzled
    __shared__ ushort sP[64][72];
    int bid = blockIdx.x;
    int h = bid & 7, ch = (bid >> 3) & 63, n = bid >> 9;
    const int tid = threadIdx.x, lane = tid & 63, w = tid >> 6;
    const int l15 = lane & 15, quad = lane >> 4;
    const size_t rowbase = (size_t)n*TT + (size_t)ch*64;
    for (int i = 0; i < 2; ++i){
        int slot = i*256 + tid;
        int r = slot >> 3, k8 = slot & 7, kk = k8 ^ (r & 7);
        int lbase = (i*256 + (tid & ~63)) * 8;
        const ushort* gq = P + (rowbase + r)*CQK + h*64 + kk*8;
        gload16(gq,        sQ + lbase);
        gload16(gq + 512,  sK + lbase);
        const ushort* gv = Vt + (((size_t)n*8 + h)*64 + r)*TT + ch*64 + kk*8;
        gload16(gv,        sV + lbase);
    }
    __syncthreads();
    const int m0w = w*16;
    short8 aQ[2]; f32x4 accS[4] = {};
    for (int ks = 0; ks < 2; ++ks){
        int m = m0w + l15;
        aQ[ks] = *(const short8*)&sQ[(m*8 + ((ks*4 + quad) ^ (m & 7)))*8];
    }
    for (int ni = 0; ni < 4; ++ni)
        for (int ks = 0; ks < 2; ++ks){
            int m = ni*16 + l15;
            short8 bK = *(const short8*)&sK[(m*8 + ((ks*4 + quad) ^ (m & 7)))*8];
            accS[ni] = __builtin_amdgcn_mfma_f32_16x16x32_bf16(aQ[ks], bK, accS[ni], 0,0,0);
        }
    float madd[4];
    for (int ni = 0; ni < 4; ++ni){
        float mv = masks[(size_t)n*TT + ch*64 + ni*16 + l15];
        madd[ni] = (mv > 0.f) ? 0.f : -1e9f;
    }
    float s[4][4];
    for (int ni = 0; ni < 4; ++ni)
        for (int r = 0; r < 4; ++r) s[ni][r] = accS[ni][r]*0.125f + madd[ni];
    float ex[4][4];
    for (int r = 0; r < 4; ++r){
        float m1 = fmaxf(fmaxf(s[0][r], s[1][r]), fmaxf(s[2][r], s[3][r]));
        for (int d = 1; d < 16; d <<= 1) m1 = fmaxf(m1, __shfl_xor(m1, d));
        float a = 0.f;
        for (int ni = 0; ni < 4; ++ni){ float e = __expf(s[ni][r] - m1); ex[ni][r] = e; a += e; }
        for (int d = 1; d < 16; d <<= 1) a += __shfl_xor(a, d);
        float rs = 1.0f / a;
        for (int ni = 0; ni < 4; ++ni)
            sP[m0w + quad*4 + r][ni*16 + l15] = f2bf(ex[ni][r] * rs);
    }
    short8 aP[2]; f32x4 accO[4] = {};
    for (int ks = 0; ks < 2; ++ks)
        aP[ks] = *(const short8*)&sP[m0w + l15][ks*32 + quad*8];
    for (int ni = 0; ni < 4; ++ni)
        for (int ks = 0; ks < 2; ++ks){
            int m = ni*16 + l15;
            short8 bV = *(const short8*)&sV[(m*8 + ((ks*4 + quad) ^ (m & 7)))*8];
            accO[ni] = __builtin_amdgcn_mfma_f32_16x16x32_bf16(aP[ks], bV, accO[ni], 0,0,0);
        }
    for (int ni = 0; ni < 4; ++ni)
        for (int r = 0; r < 4; ++r){
            size_t row = rowbase + m0w + quad*4 + r;
            ctx[row*CC + h*64 + ni*16 + l15] = f2bf(accO[ni][r]);
        }
}

// ---------------- K3: out-projection, 128m x 64co tiles ----------------
__global__ __launch_bounds__(256) void out_gemm(const ushort* __restrict__ ctx,
                                                const ushort* __restrict__ Wob,
                                                const float* __restrict__ b_out,
                                                const float* __restrict__ x,
                                                const float* __restrict__ masks,
                                                float* __restrict__ out){
    __shared__ ushort sA[128*64];
    __shared__ ushort sB[64*64];
    const int tid = threadIdx.x;
    const int bid = blockIdx.x;
    const int mtile  = ((bid & 7) << 4) | ((bid >> 3) & 15);
    const int cotile = bid >> 7;               // 0..7
    const int co0 = cotile * 64;
    const int m0  = mtile * 128;
    const int n = m0 >> 12, t0 = m0 & 4095;
    const ushort* Abase = ctx + (size_t)m0*CC;
    const ushort* Bbase = Wob + (size_t)co0*CC;
    const int w = tid >> 6, lane = tid & 63;
    const int wr = w >> 1, wc = w & 1;
    const int l15 = lane & 15, quad = lane >> 4;

    const ushort* gA[4]; ushort* lA[4];
    const ushort* gB[2]; ushort* lB[2];
    for (int i = 0; i < 4; ++i){
        int slot = i*256 + tid;
        int m = slot >> 3, k8 = slot & 7, kk = k8 ^ (m & 7);
        gA[i] = Abase + (size_t)m*CC + kk*8;
        lA[i] = sA + (i*256 + (tid & ~63)) * 8;
    }
    for (int i = 0; i < 2; ++i){
        int slot = i*256 + tid;
        int m = slot >> 3, k8 = slot & 7, kk = k8 ^ (m & 7);
        gB[i] = Bbase + (size_t)m*CC + kk*8;
        lB[i] = sB + (i*256 + (tid & ~63)) * 8;
    }

    f32x4 acc[4][2] = {};
    for (int kb = 0; kb < 8; ++kb){
        __syncthreads();
        for (int i = 0; i < 4; ++i) gload16(gA[i] + kb*64, lA[i]);
        for (int i = 0; i < 2; ++i) gload16(gB[i] + kb*64, lB[i]);
        __syncthreads();
        for (int ks = 0; ks < 2; ++ks){
            short8 aF[4], bF[2];
            for (int mi = 0; mi < 4; ++mi){
                int m = wr*64 + mi*16 + l15;
                aF[mi] = *(const short8*)&sA[(m*8 + ((ks*4 + quad) ^ (m & 7)))*8];
            }
            for (int ni = 0; ni < 2; ++ni){
                int m = wc*32 + ni*16 + l15;
                bF[ni] = *(const short8*)&sB[(m*8 + ((ks*4 + quad) ^ (m & 7)))*8];
            }
            for (int mi = 0; mi < 4; ++mi)
                for (int ni = 0; ni < 2; ++ni)
                    acc[mi][ni] = __builtin_amdgcn_mfma_f32_16x16x32_bf16(
                        aF[mi], bF[ni], acc[mi][ni], 0, 0, 0);
        }
    }
    float bo[2];
    for (int ni = 0; ni < 2; ++ni) bo[ni] = b_out[co0 + wc*32 + ni*16 + l15];
    for (int mi = 0; mi < 4; ++mi){
        int t = t0 + wr*64 + mi*16 + quad*4;
        f32x4 mk = *(const f32x4*)(masks + (size_t)n*TT + t);
        for (int ni = 0; ni < 2; ++ni){
            int co = co0 + wc*32 + ni*16 + l15;
            const f32x4 xv = *(const f32x4*)(x + ((size_t)n*CC + co)*TT + t);
            f32x4 o;
            for (int r = 0; r < 4; ++r)
                o[r] = (acc[mi][ni][r] + bo[ni]) * mk[r] + xv[r];
            *(f32x4*)(out + ((size_t)n*CC + co)*TT + t) = o;
        }
    }
}

// ---------------- K4: InstanceNorm over T per (n,c), in place ----------------
__global__ __launch_bounds__(256) void inorm(float* __restrict__ out){
    __shared__ float sS[4], sQ2[4];
    float* row = out + (size_t)blockIdx.x * TT;
    f32x4 vbuf[4];
    float s = 0.f, ss = 0.f;
    for (int i = 0; i < 4; ++i){
        f32x4 vv = *(const f32x4*)(row + (size_t)(i*256 + threadIdx.x)*4);
        vbuf[i] = vv;
        for (int r = 0; r < 4; ++r){ s += vv[r]; ss += vv[r]*vv[r]; }
    }
    for (int d = 1; d < 64; d <<= 1){ s += __shfl_xor(s, d); ss += __shfl_xor(ss, d); }
    int w = threadIdx.x >> 6;
    if ((threadIdx.x & 63) == 0){ sS[w] = s; sQ2[w] = ss; }
    __syncthreads();
    s  = sS[0] + sS[1] + sS[2] + sS[3];
    ss = sQ2[0] + sQ2[1] + sQ2[2] + sQ2[3];
    float mean = s * (1.0f/TT);
    float var  = ss * (1.0f/TT) - mean*mean;
    float rstd = rsqrtf(var + 1e-5f);
    for (int i = 0; i < 4; ++i){
        f32x4 vv = vbuf[i], o;
        for (int r = 0; r < 4; ++r) o[r] = (vv[r] - mean) * rstd;
        *(f32x4*)(row + (size_t)(i*256 + threadIdx.x)*4) = o;
    }
}

extern "C" void kernel_launch(void* const* d_in, const int* in_sizes, int n_in,
                              void* d_out, int out_size, void* d_ws, size_t ws_size,
                              hipStream_t stream) {
    const float* x     = (const float*)d_in[0];
    const float* q     = (const float*)d_in[1];
    const float* k     = (const float*)d_in[2];
    const float* v     = (const float*)d_in[3];
    const float* masks = (const float*)d_in[4];
    const float* W_in  = (const float*)d_in[5];
    const float* b_in  = (const float*)d_in[6];
    const float* W_out = (const float*)d_in[7];
    const float* b_out = (const float*)d_in[8];
    float* out = (float*)d_out;

    ushort* ws  = (ushort*)d_ws;
    ushort* XT  = ws;                           // 3*NTC bf16 (q,k,v transposed)
    ushort* Wb  = ws + (size_t)3*NTC;           // 786432
    ushort* Wob = Wb + 786432;                  // 262144
    ushort* P   = Wob + 262144;                 // NB*TT*CQK (Q,K projected)
    ushort* Vt  = P + (size_t)NB*TT*CQK;        // NTC (V projected, transposed)
    ushort* ctx = ws;                           // aliases XT (free after proj_gemm)

    prep<<<3328, 256, 0, stream>>>(q, k, v, W_in, W_out, XT, Wb, Wob);
    proj_gemm<<<1536, 256, 0, stream>>>(XT, Wb, b_in, P, Vt);
    attn_kernel<<<2048, 256, 0, stream>>>(P, Vt, masks, ctx);
    out_gemm<<<1024, 256, 0, stream>>>(ctx, Wob, b_out, x, masks, out);
    inorm<<<2048, 256, 0, stream>>>(out);
}

// Round 5
// 255.306 us; speedup vs baseline: 1.0541x; 1.0195x over previous
//
#include <hip/hip_runtime.h>
#include <hip/hip_bf16.h>

#define NB 4
#define CC 512
#define TT 4096
#define C3 1536
#define CQK 1024
#define NTC (NB*TT*CC)   // 8388608 elems per [N,T,C] tensor

typedef __attribute__((ext_vector_type(4))) float f32x4;
typedef __attribute__((ext_vector_type(8))) short short8;
typedef unsigned short ushort;
typedef __attribute__((ext_vector_type(8))) ushort u16x8;

__device__ __forceinline__ ushort f2bf(float f){
    union { float f; unsigned u; } x; x.f = f;
    unsigned r = x.u + 0x7fffu + ((x.u >> 16) & 1u);   // RNE
    return (ushort)(r >> 16);
}

__device__ __forceinline__ ushort2 pk2bf(float a, float b){
    float2 f2; f2.x = a; f2.y = b;
    __hip_bfloat162 h = __float22bfloat162_rn(f2);     // v_cvt_pk_bf16_f32 (RNE)
    union { __hip_bfloat162 h2; ushort2 u2; } u; u.h2 = h;
    return u.u2;
}

__device__ __forceinline__ void gload16(const void* g, void* l){
    __builtin_amdgcn_global_load_lds((const __attribute__((address_space(1))) void*)g,
                                     (__attribute__((address_space(3))) void*)l,
                                     16, 0, 0);
}

// ---------------- K0: prep = q/k/v transpose+cvt (register micro-transpose) + weight cvt ----------------
__global__ __launch_bounds__(256) void prep(const float* __restrict__ q,
                                            const float* __restrict__ k,
                                            const float* __restrict__ v,
                                            const float* __restrict__ Wi,
                                            const float* __restrict__ Wo,
                                            ushort* __restrict__ XT,
                                            ushort* __restrict__ Wb,
                                            ushort* __restrict__ Wob){
    const int tid = threadIdx.x;
    int b = blockIdx.x;
    if (b >= 3072){
        int idx0 = (b - 3072) * 1024 + tid;
        for (int i = 0; i < 4; ++i){
            int idx = idx0 + i*256;
            const float* src; ushort* dst; int j;
            if (idx < 196608){ src = Wi; dst = Wb;  j = idx; }
            else             { src = Wo; dst = Wob; j = idx - 196608; }
            f32x4 vv = *((const f32x4*)src + j);
            ushort4 o;
            *(ushort2*)&o.x = pk2bf(vv[0], vv[1]);
            *(ushort2*)&o.z = pk2bf(vv[2], vv[3]);
            *((ushort4*)dst + j) = o;
        }
        return;
    }
    int tq  = b & 31;        // t-chunk of 128
    int cch = (b >> 5) & 7;  // c-chunk of 64
    int n   = (b >> 8) & 3;
    int which = b >> 10;     // 0=q 1=k 2=v
    const float* src = (which == 0) ? q : (which == 1) ? k : v;
    const int c0   = (tid & 7) * 8;      // 8 c-rows per thread
    const int trel = (tid >> 3) * 4;     // 4 t per thread
    const float* base = src + (size_t)n*CC*TT + (size_t)(cch*64 + c0)*TT + (size_t)tq*128 + trel;

    f32x4 cur[8];
    #pragma unroll
    for (int j = 0; j < 8; ++j)
        cur[j] = *(const f32x4*)(base + (size_t)j*TT);

    ushort* dst = XT + (size_t)which*NTC
                + ((size_t)n*TT + (size_t)tq*128 + trel)*CC + cch*64 + c0;
    #pragma unroll
    for (int tj = 0; tj < 4; ++tj){
        u16x8 o;
        #pragma unroll
        for (int j = 0; j < 8; j += 2){
            ushort2 p = pk2bf(cur[j][tj], cur[j+1][tj]);
            o[j] = p.x; o[j+1] = p.y;
        }
        *(u16x8*)(dst + (size_t)tj*CC) = o;
    }
}

// ---------------- K1: packed QKV projection GEMM (m97 staging + LDS epilogue) ----------------
__global__ __launch_bounds__(256) void proj_gemm(const ushort* __restrict__ XT,
                                                 const ushort* __restrict__ Wb,
                                                 const float* __restrict__ b_in,
                                                 ushort* __restrict__ P,
                                                 ushort* __restrict__ Vt){
    __shared__ __align__(16) ushort smem[128*136];   // 34816 B: staging (16K+16K) then out tile
    ushort* sA = smem;            // 128*64
    ushort* sB = smem + 128*64;   // 128*64
    const int tid = threadIdx.x;
    const int bid = blockIdx.x;
    const int mtile  = ((bid & 7) << 4) | ((bid >> 3) & 15);
    const int cotile = bid >> 7;               // 0..11
    const int co0 = cotile * 128;
    const int m0  = mtile * 128;
    const int which = co0 >> 9;                // 0:q 1:k 2:v
    const ushort* Abase = XT + (size_t)which*NTC + (size_t)m0*CC;
    const ushort* Bbase = Wb + (size_t)co0*CC;
    const int w = tid >> 6, lane = tid & 63;
    const int wr = w >> 1, wc = w & 1;
    const int l15 = lane & 15, quad = lane >> 4;

    const ushort* gA[4]; const ushort* gB[4];
    ushort* lA[4]; ushort* lB[4];
    for (int i = 0; i < 4; ++i){
        int slot = i*256 + tid;
        int m = slot >> 3, k8 = slot & 7, kk = k8 ^ (m & 7);
        gA[i] = Abase + (size_t)m*CC + kk*8;
        gB[i] = Bbase + (size_t)m*CC + kk*8;
        int lbase = (i*256 + (tid & ~63)) * 8;
        lA[i] = sA + lbase;  lB[i] = sB + lbase;
    }

    f32x4 acc[4][4] = {};
    for (int kb = 0; kb < 8; ++kb){
        __syncthreads();
        for (int i = 0; i < 4; ++i){
            gload16(gA[i] + kb*64, lA[i]);
            gload16(gB[i] + kb*64, lB[i]);
        }
        __syncthreads();
        for (int ks = 0; ks < 2; ++ks){
            short8 aF[4], bF[4];
            for (int mi = 0; mi < 4; ++mi){
                int m = wr*64 + mi*16 + l15;
                aF[mi] = *(const short8*)&sA[(m*8 + ((ks*4 + quad) ^ (m & 7)))*8];
            }
            for (int ni = 0; ni < 4; ++ni){
                int m = wc*64 + ni*16 + l15;
                bF[ni] = *(const short8*)&sB[(m*8 + ((ks*4 + quad) ^ (m & 7)))*8];
            }
            for (int mi = 0; mi < 4; ++mi)
                for (int ni = 0; ni < 4; ++ni)
                    acc[mi][ni] = __builtin_amdgcn_mfma_f32_16x16x32_bf16(
                        aF[mi], bF[ni], acc[mi][ni], 0, 0, 0);
        }
    }

    float bj[4];
    for (int ni = 0; ni < 4; ++ni) bj[ni] = b_in[co0 + wc*64 + ni*16 + l15];

    __syncthreads();                 // done reading sA/sB; reuse as sOut[128][136]
    ushort* sOut = smem;
    if (which < 2){
        // sOut[m][co]
        for (int mi = 0; mi < 4; ++mi){
            int mrow = wr*64 + mi*16 + quad*4;
            for (int ni = 0; ni < 4; ++ni){
                int col = wc*64 + ni*16 + l15;
                for (int r = 0; r < 4; ++r)
                    sOut[(mrow + r)*136 + col] = f2bf(acc[mi][ni][r] + bj[ni]);
            }
        }
    } else {
        // sOut[co][m]  (transposed for Vt)
        for (int mi = 0; mi < 4; ++mi){
            int mrow = wr*64 + mi*16 + quad*4;
            for (int ni = 0; ni < 4; ++ni){
                int col = wc*64 + ni*16 + l15;
                for (int r = 0; r < 4; ++r)
                    sOut[col*136 + mrow + r] = f2bf(acc[mi][ni][r] + bj[ni]);
            }
        }
    }
    __syncthreads();
    if (which < 2){
        for (int i = 0; i < 8; ++i){
            int flat = i*256 + tid;
            int row = flat >> 4, cs = (flat & 15)*8;
            u16x8 val = *(const u16x8*)&sOut[row*136 + cs];
            *(u16x8*)(P + (size_t)(m0 + row)*CQK + which*512 + (co0 & 511) + cs) = val;
        }
    } else {
        int n = m0 >> 12, t0 = m0 & 4095;
        for (int i = 0; i < 8; ++i){
            int flat = i*256 + tid;
            int row = flat >> 4, cs = (flat & 15)*8;    // row = local co (d), cs along t
            int cl = (co0 - 1024) + row;
            int h = cl >> 6, d = cl & 63;
            u16x8 val = *(const u16x8*)&sOut[row*136 + cs];
            *(u16x8*)(Vt + (((size_t)n*8 + h)*64 + d)*TT + t0 + cs) = val;
        }
    }
}

// ---------------- K2: per-(n,chunk,head) attention (LDS epilogue) ----------------
__global__ __launch_bounds__(256) void attn_kernel(const ushort* __restrict__ P,
                                                   const ushort* __restrict__ Vt,
                                                   const float* __restrict__ masks,
                                                   ushort* __restrict__ ctx){
    __shared__ __align__(16) ushort sQ[64*64], sK[64*64], sV[64*64];   // swizzled
    __shared__ __align__(16) ushort sP[64][72];
    __shared__ __align__(16) ushort sO[64*72];
    int bid = blockIdx.x;
    int h = bid & 7, ch = (bid >> 3) & 63, n = bid >> 9;
    const int tid = threadIdx.x, lane = tid & 63, w = tid >> 6;
    const int l15 = lane & 15, quad = lane >> 4;
    const size_t rowbase = (size_t)n*TT + (size_t)ch*64;
    for (int i = 0; i < 2; ++i){
        int slot = i*256 + tid;
        int r = slot >> 3, k8 = slot & 7, kk = k8 ^ (r & 7);
        int lbase = (i*256 + (tid & ~63)) * 8;
        const ushort* gq = P + (rowbase + r)*CQK + h*64 + kk*8;
        gload16(gq,        sQ + lbase);
        gload16(gq + 512,  sK + lbase);
        const ushort* gv = Vt + (((size_t)n*8 + h)*64 + r)*TT + ch*64 + kk*8;
        gload16(gv,        sV + lbase);
    }
    __syncthreads();
    const int m0w = w*16;
    short8 aQ[2]; f32x4 accS[4] = {};
    for (int ks = 0; ks < 2; ++ks){
        int m = m0w + l15;
        aQ[ks] = *(const short8*)&sQ[(m*8 + ((ks*4 + quad) ^ (m & 7)))*8];
    }
    for (int ni = 0; ni < 4; ++ni)
        for (int ks = 0; ks < 2; ++ks){
            int m = ni*16 + l15;
            short8 bK = *(const short8*)&sK[(m*8 + ((ks*4 + quad) ^ (m & 7)))*8];
            accS[ni] = __builtin_amdgcn_mfma_f32_16x16x32_bf16(aQ[ks], bK, accS[ni], 0,0,0);
        }
    float madd[4];
    for (int ni = 0; ni < 4; ++ni){
        float mv = masks[(size_t)n*TT + ch*64 + ni*16 + l15];
        madd[ni] = (mv > 0.f) ? 0.f : -1e9f;
    }
    float s[4][4];
    for (int ni = 0; ni < 4; ++ni)
        for (int r = 0; r < 4; ++r) s[ni][r] = accS[ni][r]*0.125f + madd[ni];
    float ex[4][4];
    for (int r = 0; r < 4; ++r){
        float m1 = fmaxf(fmaxf(s[0][r], s[1][r]), fmaxf(s[2][r], s[3][r]));
        for (int d = 1; d < 16; d <<= 1) m1 = fmaxf(m1, __shfl_xor(m1, d));
        float a = 0.f;
        for (int ni = 0; ni < 4; ++ni){ float e = __expf(s[ni][r] - m1); ex[ni][r] = e; a += e; }
        for (int d = 1; d < 16; d <<= 1) a += __shfl_xor(a, d);
        float rs = 1.0f / a;
        for (int ni = 0; ni < 4; ++ni)
            sP[m0w + quad*4 + r][ni*16 + l15] = f2bf(ex[ni][r] * rs);
    }
    short8 aP[2]; f32x4 accO[4] = {};
    for (int ks = 0; ks < 2; ++ks)
        aP[ks] = *(const short8*)&sP[m0w + l15][ks*32 + quad*8];
    for (int ni = 0; ni < 4; ++ni)
        for (int ks = 0; ks < 2; ++ks){
            int m = ni*16 + l15;
            short8 bV = *(const short8*)&sV[(m*8 + ((ks*4 + quad) ^ (m & 7)))*8];
            accO[ni] = __builtin_amdgcn_mfma_f32_16x16x32_bf16(aP[ks], bV, accO[ni], 0,0,0);
        }
    // O -> LDS tile, then vectorized 128B-row stores
    for (int ni = 0; ni < 4; ++ni)
        for (int r = 0; r < 4; ++r)
            sO[(m0w + quad*4 + r)*72 + ni*16 + l15] = f2bf(accO[ni][r]);
    __syncthreads();
    for (int i = 0; i < 2; ++i){
        int flat = i*256 + tid;
        int row = flat >> 3, cs = (flat & 7)*8;
        u16x8 val = *(const u16x8*)&sO[row*72 + cs];
        *(u16x8*)(ctx + (rowbase + row)*CC + h*64 + cs) = val;
    }
}

// ---------------- K3: out-projection, 128m x 64co tiles, LDS epilogue ----------------
__global__ __launch_bounds__(256) void out_gemm(const ushort* __restrict__ ctx,
                                                const ushort* __restrict__ Wob,
                                                const float* __restrict__ b_out,
                                                const float* __restrict__ x,
                                                const float* __restrict__ masks,
                                                float* __restrict__ out){
    __shared__ __align__(16) ushort smem[16896];   // 33792 B: staging (16K+8K) then f32 out tile
    ushort* sA = smem;            // 128*64
    ushort* sB = smem + 128*64;   // 64*64
    float* fOut = (float*)smem;   // [64 co][132] f32
    const int tid = threadIdx.x;
    const int bid = blockIdx.x;
    const int mtile  = ((bid & 7) << 4) | ((bid >> 3) & 15);
    const int cotile = bid >> 7;               // 0..7
    const int co0 = cotile * 64;
    const int m0  = mtile * 128;
    const int n = m0 >> 12, t0 = m0 & 4095;
    const ushort* Abase = ctx + (size_t)m0*CC;
    const ushort* Bbase = Wob + (size_t)co0*CC;
    const int w = tid >> 6, lane = tid & 63;
    const int wr = w >> 1, wc = w & 1;
    const int l15 = lane & 15, quad = lane >> 4;

    const ushort* gA[4]; ushort* lA[4];
    const ushort* gB[2]; ushort* lB[2];
    for (int i = 0; i < 4; ++i){
        int slot = i*256 + tid;
        int m = slot >> 3, k8 = slot & 7, kk = k8 ^ (m & 7);
        gA[i] = Abase + (size_t)m*CC + kk*8;
        lA[i] = sA + (i*256 + (tid & ~63)) * 8;
    }
    for (int i = 0; i < 2; ++i){
        int slot = i*256 + tid;
        int m = slot >> 3, k8 = slot & 7, kk = k8 ^ (m & 7);
        gB[i] = Bbase + (size_t)m*CC + kk*8;
        lB[i] = sB + (i*256 + (tid & ~63)) * 8;
    }

    f32x4 acc[4][2] = {};
    for (int kb = 0; kb < 8; ++kb){
        __syncthreads();
        for (int i = 0; i < 4; ++i) gload16(gA[i] + kb*64, lA[i]);
        for (int i = 0; i < 2; ++i) gload16(gB[i] + kb*64, lB[i]);
        __syncthreads();
        for (int ks = 0; ks < 2; ++ks){
            short8 aF[4], bF[2];
            for (int mi = 0; mi < 4; ++mi){
                int m = wr*64 + mi*16 + l15;
                aF[mi] = *(const short8*)&sA[(m*8 + ((ks*4 + quad) ^ (m & 7)))*8];
            }
            for (int ni = 0; ni < 2; ++ni){
                int m = wc*32 + ni*16 + l15;
                bF[ni] = *(const short8*)&sB[(m*8 + ((ks*4 + quad) ^ (m & 7)))*8];
            }
            for (int mi = 0; mi < 4; ++mi)
                for (int ni = 0; ni < 2; ++ni)
                    acc[mi][ni] = __builtin_amdgcn_mfma_f32_16x16x32_bf16(
                        aF[mi], bF[ni], acc[mi][ni], 0, 0, 0);
        }
    }
    float bo[2];
    for (int ni = 0; ni < 2; ++ni) bo[ni] = b_out[co0 + wc*32 + ni*16 + l15];

    __syncthreads();                 // staging done; reuse LDS as fOut[co][t]
    for (int mi = 0; mi < 4; ++mi){
        int tl = wr*64 + mi*16 + quad*4;
        for (int ni = 0; ni < 2; ++ni){
            int cl = wc*32 + ni*16 + l15;
            f32x4 vv;
            for (int r = 0; r < 4; ++r) vv[r] = acc[mi][ni][r] + bo[ni];
            *(f32x4*)&fOut[cl*132 + tl] = vv;
        }
    }
    __syncthreads();
    for (int i = 0; i < 8; ++i){
        int flat = i*256 + tid;
        int co = flat >> 5, ts = (flat & 31)*4;
        f32x4 a = *(const f32x4*)&fOut[co*132 + ts];
        f32x4 mk = *(const f32x4*)(masks + (size_t)n*TT + t0 + ts);
        f32x4 xv = *(const f32x4*)(x + ((size_t)n*CC + co0 + co)*TT + t0 + ts);
        f32x4 o;
        for (int r = 0; r < 4; ++r) o[r] = a[r]*mk[r] + xv[r];
        *(f32x4*)(out + ((size_t)n*CC + co0 + co)*TT + t0 + ts) = o;
    }
}

// ---------------- K4: InstanceNorm over T per (n,c), in place ----------------
__global__ __launch_bounds__(256) void inorm(float* __restrict__ out){
    __shared__ float sS[4], sQ2[4];
    float* row = out + (size_t)blockIdx.x * TT;
    f32x4 vbuf[4];
    float s = 0.f, ss = 0.f;
    for (int i = 0; i < 4; ++i){
        f32x4 vv = *(const f32x4*)(row + (size_t)(i*256 + threadIdx.x)*4);
        vbuf[i] = vv;
        for (int r = 0; r < 4; ++r){ s += vv[r]; ss += vv[r]*vv[r]; }
    }
    for (int d = 1; d < 64; d <<= 1){ s += __shfl_xor(s, d); ss += __shfl_xor(ss, d); }
    int w = threadIdx.x >> 6;
    if ((threadIdx.x & 63) == 0){ sS[w] = s; sQ2[w] = ss; }
    __syncthreads();
    s  = sS[0] + sS[1] + sS[2] + sS[3];
    ss = sQ2[0] + sQ2[1] + sQ2[2] + sQ2[3];
    float mean = s * (1.0f/TT);
    float var  = ss * (1.0f/TT) - mean*mean;
    float rstd = rsqrtf(var + 1e-5f);
    for (int i = 0; i < 4; ++i){
        f32x4 vv = vbuf[i], o;
        for (int r = 0; r < 4; ++r) o[r] = (vv[r] - mean) * rstd;
        *(f32x4*)(row + (size_t)(i*256 + threadIdx.x)*4) = o;
    }
}

extern "C" void kernel_launch(void* const* d_in, const int* in_sizes, int n_in,
                              void* d_out, int out_size, void* d_ws, size_t ws_size,
                              hipStream_t stream) {
    const float* x     = (const float*)d_in[0];
    const float* q     = (const float*)d_in[1];
    const float* k     = (const float*)d_in[2];
    const float* v     = (const float*)d_in[3];
    const float* masks = (const float*)d_in[4];
    const float* W_in  = (const float*)d_in[5];
    const float* b_in  = (const float*)d_in[6];
    const float* W_out = (const float*)d_in[7];
    const float* b_out = (const float*)d_in[8];
    float* out = (float*)d_out;

    ushort* ws  = (ushort*)d_ws;
    ushort* XT  = ws;                           // 3*NTC bf16 (q,k,v transposed)
    ushort* Wb  = ws + (size_t)3*NTC;           // 786432
    ushort* Wob = Wb + 786432;                  // 262144
    ushort* P   = Wob + 262144;                 // NB*TT*CQK (Q,K projected)
    ushort* Vt  = P + (size_t)NB*TT*CQK;        // NTC (V projected, transposed)
    ushort* ctx = ws;                           // aliases XT (free after proj_gemm)

    prep<<<3328, 256, 0, stream>>>(q, k, v, W_in, W_out, XT, Wb, Wob);
    proj_gemm<<<1536, 256, 0, stream>>>(XT, Wb, b_in, P, Vt);
    attn_kernel<<<2048, 256, 0, stream>>>(P, Vt, masks, ctx);
    out_gemm<<<1024, 256, 0, stream>>>(ctx, Wob, b_out, x, masks, out);
    inorm<<<2048, 256, 0, stream>>>(out);
}

// Round 6
// 245.132 us; speedup vs baseline: 1.0979x; 1.0415x over previous
//
#include <hip/hip_runtime.h>
#include <hip/hip_bf16.h>

#define NB 4
#define CC 512
#define TT 4096
#define C3 1536
#define CQK 1024
#define NTC (NB*TT*CC)   // 8388608 elems per [N,T,C] tensor

typedef __attribute__((ext_vector_type(4))) float f32x4;
typedef __attribute__((ext_vector_type(8))) short short8;
typedef unsigned short ushort;
typedef __attribute__((ext_vector_type(8))) ushort u16x8;

__device__ __forceinline__ ushort f2bf(float f){
    union { float f; unsigned u; } x; x.f = f;
    unsigned r = x.u + 0x7fffu + ((x.u >> 16) & 1u);   // RNE
    return (ushort)(r >> 16);
}

__device__ __forceinline__ ushort2 pk2bf(float a, float b){
    float2 f2; f2.x = a; f2.y = b;
    __hip_bfloat162 h = __float22bfloat162_rn(f2);     // v_cvt_pk_bf16_f32 (RNE)
    union { __hip_bfloat162 h2; ushort2 u2; } u; u.h2 = h;
    return u.u2;
}

__device__ __forceinline__ void gload16(const void* g, void* l){
    __builtin_amdgcn_global_load_lds((const __attribute__((address_space(1))) void*)g,
                                     (__attribute__((address_space(3))) void*)l,
                                     16, 0, 0);
}

// sA swizzle: 16B slot position for logical c-block cb at row m.
// pos=(cb+m+(m>>3))&7 -> 2-way (free) for both write lanes (m stride 4) and
// fragment-read lanes (m stride 1).
__device__ __forceinline__ int apos(int m, int cb){
    return (m*8 + ((cb + m + (m >> 3)) & 7))*8;
}

// ---------------- K0: weight fp32 -> bf16 ----------------
__global__ __launch_bounds__(256) void wcvt(const float* __restrict__ Wi,
                                            const float* __restrict__ Wo,
                                            ushort* __restrict__ Wb,
                                            ushort* __restrict__ Wob){
    int idx0 = blockIdx.x * 1024 + threadIdx.x;
    for (int i = 0; i < 4; ++i){
        int idx = idx0 + i*256;
        const float* src; ushort* dst; int j;
        if (idx < 196608){ src = Wi; dst = Wb;  j = idx; }
        else             { src = Wo; dst = Wob; j = idx - 196608; }
        f32x4 vv = *((const f32x4*)src + j);
        ushort4 o;
        *(ushort2*)&o.x = pk2bf(vv[0], vv[1]);
        *(ushort2*)&o.z = pk2bf(vv[2], vv[3]);
        *((ushort4*)dst + j) = o;
    }
}

// ---------------- K1: fused transpose+cvt + QKV projection GEMM ----------------
// A read directly from q/k/v fp32 [N,C,T]; register micro-transpose -> sA (bf16).
// B (weights bf16) staged via global_load_lds. Q,K -> P[m][1024]; V -> Vt[n][h][d][t].
__global__ __launch_bounds__(256) void proj_gemm(const float* __restrict__ q,
                                                 const float* __restrict__ k,
                                                 const float* __restrict__ v,
                                                 const ushort* __restrict__ Wb,
                                                 const float* __restrict__ b_in,
                                                 ushort* __restrict__ P,
                                                 ushort* __restrict__ Vt){
    __shared__ __align__(16) ushort smem[128*136];   // sA 16K + sB 16K, then sOut[128][136]
    ushort* sA = smem;            // 128 rows x 8 slots x 8 ushorts
    ushort* sB = smem + 128*64;
    const int tid = threadIdx.x;
    const int bid = blockIdx.x;
    const int mtile  = ((bid & 7) << 4) | ((bid >> 3) & 15);
    const int cotile = bid >> 7;               // 0..11
    const int co0 = cotile * 128;
    const int m0  = mtile * 128;
    const int which = co0 >> 9;                // 0:q 1:k 2:v
    const float* src = (which == 0) ? q : (which == 1) ? k : v;
    const int n  = m0 >> 12, t0 = m0 & 4095;
    const ushort* Bbase = Wb + (size_t)co0*CC;
    const int w = tid >> 6, lane = tid & 63;
    const int wr = w >> 1, wc = w & 1;
    const int l15 = lane & 15, quad = lane >> 4;

    // A staging: wave w covers c-rows [w*16, w*16+16), cb = 2w + (lane>>5), t = (lane&31)*4+tj
    const int cbA = (w << 1) | (lane >> 5);
    const int tA  = lane & 31;
    const float* Abase = src + (size_t)n*CC*TT + (size_t)(cbA*8)*TT + t0 + tA*4;

    // B staging slots (16 KB per kb, 4 insts/thread)
    const ushort* gB[4]; ushort* lB[4];
    for (int i = 0; i < 4; ++i){
        int slot = i*256 + tid;
        int mr = slot >> 3, k8 = slot & 7, kk = k8 ^ (mr & 7);
        gB[i] = Bbase + (size_t)mr*CC + kk*8;
        lB[i] = sB + (i*256 + (tid & ~63)) * 8;
    }

    f32x4 acc[4][4] = {};
    for (int kb = 0; kb < 8; ++kb){
        f32x4 cur[8];
        const float* Ab = Abase + (size_t)(kb*64)*TT;
        #pragma unroll
        for (int j = 0; j < 8; ++j)
            cur[j] = *(const f32x4*)(Ab + (size_t)j*TT);
        __syncthreads();
        #pragma unroll
        for (int tj = 0; tj < 4; ++tj){
            int m = tA*4 + tj;
            u16x8 o;
            #pragma unroll
            for (int j = 0; j < 8; j += 2){
                ushort2 p = pk2bf(cur[j][tj], cur[j+1][tj]);
                o[j] = p.x; o[j+1] = p.y;
            }
            *(u16x8*)&sA[apos(m, cbA)] = o;
        }
        for (int i = 0; i < 4; ++i) gload16(gB[i] + kb*64, lB[i]);
        __syncthreads();
        for (int ks = 0; ks < 2; ++ks){
            short8 aF[4], bF[4];
            for (int mi = 0; mi < 4; ++mi){
                int m = wr*64 + mi*16 + l15;
                aF[mi] = *(const short8*)&sA[apos(m, ks*4 + quad)];
            }
            for (int ni = 0; ni < 4; ++ni){
                int m = wc*64 + ni*16 + l15;
                bF[ni] = *(const short8*)&sB[(m*8 + ((ks*4 + quad) ^ (m & 7)))*8];
            }
            for (int mi = 0; mi < 4; ++mi)
                for (int ni = 0; ni < 4; ++ni)
                    acc[mi][ni] = __builtin_amdgcn_mfma_f32_16x16x32_bf16(
                        aF[mi], bF[ni], acc[mi][ni], 0, 0, 0);
        }
    }

    float bj[4];
    for (int ni = 0; ni < 4; ++ni) bj[ni] = b_in[co0 + wc*64 + ni*16 + l15];

    __syncthreads();                 // done with sA/sB; reuse as sOut[128][136]
    ushort* sOut = smem;
    if (which < 2){
        for (int mi = 0; mi < 4; ++mi){
            int mrow = wr*64 + mi*16 + quad*4;
            for (int ni = 0; ni < 4; ++ni){
                int col = wc*64 + ni*16 + l15;
                for (int r = 0; r < 4; ++r)
                    sOut[(mrow + r)*136 + col] = f2bf(acc[mi][ni][r] + bj[ni]);
            }
        }
    } else {
        for (int mi = 0; mi < 4; ++mi){
            int mrow = wr*64 + mi*16 + quad*4;
            for (int ni = 0; ni < 4; ++ni){
                int col = wc*64 + ni*16 + l15;
                for (int r = 0; r < 4; ++r)
                    sOut[col*136 + mrow + r] = f2bf(acc[mi][ni][r] + bj[ni]);
            }
        }
    }
    __syncthreads();
    if (which < 2){
        for (int i = 0; i < 8; ++i){
            int flat = i*256 + tid;
            int row = flat >> 4, cs = (flat & 15)*8;
            u16x8 val = *(const u16x8*)&sOut[row*136 + cs];
            *(u16x8*)(P + (size_t)(m0 + row)*CQK + which*512 + (co0 & 511) + cs) = val;
        }
    } else {
        for (int i = 0; i < 8; ++i){
            int flat = i*256 + tid;
            int row = flat >> 4, cs = (flat & 15)*8;    // row = local co (d), cs along t
            int cl = (co0 - 1024) + row;
            int h = cl >> 6, d = cl & 63;
            u16x8 val = *(const u16x8*)&sOut[row*136 + cs];
            *(u16x8*)(Vt + (((size_t)n*8 + h)*64 + d)*TT + t0 + cs) = val;
        }
    }
}

// ---------------- K2: per-(n,chunk,head) attention (LDS epilogue) ----------------
__global__ __launch_bounds__(256) void attn_kernel(const ushort* __restrict__ P,
                                                   const ushort* __restrict__ Vt,
                                                   const float* __restrict__ masks,
                                                   ushort* __restrict__ ctx){
    __shared__ __align__(16) ushort sQ[64*64], sK[64*64], sV[64*64];   // swizzled
    __shared__ __align__(16) ushort sP[64][72];
    __shared__ __align__(16) ushort sO[64*72];
    int bid = blockIdx.x;
    int h = bid & 7, ch = (bid >> 3) & 63, n = bid >> 9;
    const int tid = threadIdx.x, lane = tid & 63, w = tid >> 6;
    const int l15 = lane & 15, quad = lane >> 4;
    const size_t rowbase = (size_t)n*TT + (size_t)ch*64;
    for (int i = 0; i < 2; ++i){
        int slot = i*256 + tid;
        int r = slot >> 3, k8 = slot & 7, kk = k8 ^ (r & 7);
        int lbase = (i*256 + (tid & ~63)) * 8;
        const ushort* gq = P + (rowbase + r)*CQK + h*64 + kk*8;
        gload16(gq,        sQ + lbase);
        gload16(gq + 512,  sK + lbase);
        const ushort* gv = Vt + (((size_t)n*8 + h)*64 + r)*TT + ch*64 + kk*8;
        gload16(gv,        sV + lbase);
    }
    __syncthreads();
    const int m0w = w*16;
    short8 aQ[2]; f32x4 accS[4] = {};
    for (int ks = 0; ks < 2; ++ks){
        int m = m0w + l15;
        aQ[ks] = *(const short8*)&sQ[(m*8 + ((ks*4 + quad) ^ (m & 7)))*8];
    }
    for (int ni = 0; ni < 4; ++ni)
        for (int ks = 0; ks < 2; ++ks){
            int m = ni*16 + l15;
            short8 bK = *(const short8*)&sK[(m*8 + ((ks*4 + quad) ^ (m & 7)))*8];
            accS[ni] = __builtin_amdgcn_mfma_f32_16x16x32_bf16(aQ[ks], bK, accS[ni], 0,0,0);
        }
    float madd[4];
    for (int ni = 0; ni < 4; ++ni){
        float mv = masks[(size_t)n*TT + ch*64 + ni*16 + l15];
        madd[ni] = (mv > 0.f) ? 0.f : -1e9f;
    }
    float s[4][4];
    for (int ni = 0; ni < 4; ++ni)
        for (int r = 0; r < 4; ++r) s[ni][r] = accS[ni][r]*0.125f + madd[ni];
    float ex[4][4];
    for (int r = 0; r < 4; ++r){
        float m1 = fmaxf(fmaxf(s[0][r], s[1][r]), fmaxf(s[2][r], s[3][r]));
        for (int d = 1; d < 16; d <<= 1) m1 = fmaxf(m1, __shfl_xor(m1, d));
        float a = 0.f;
        for (int ni = 0; ni < 4; ++ni){ float e = __expf(s[ni][r] - m1); ex[ni][r] = e; a += e; }
        for (int d = 1; d < 16; d <<= 1) a += __shfl_xor(a, d);
        float rs = 1.0f / a;
        for (int ni = 0; ni < 4; ++ni)
            sP[m0w + quad*4 + r][ni*16 + l15] = f2bf(ex[ni][r] * rs);
    }
    short8 aP[2]; f32x4 accO[4] = {};
    for (int ks = 0; ks < 2; ++ks)
        aP[ks] = *(const short8*)&sP[m0w + l15][ks*32 + quad*8];
    for (int ni = 0; ni < 4; ++ni)
        for (int ks = 0; ks < 2; ++ks){
            int m = ni*16 + l15;
            short8 bV = *(const short8*)&sV[(m*8 + ((ks*4 + quad) ^ (m & 7)))*8];
            accO[ni] = __builtin_amdgcn_mfma_f32_16x16x32_bf16(aP[ks], bV, accO[ni], 0,0,0);
        }
    for (int ni = 0; ni < 4; ++ni)
        for (int r = 0; r < 4; ++r)
            sO[(m0w + quad*4 + r)*72 + ni*16 + l15] = f2bf(accO[ni][r]);
    __syncthreads();
    for (int i = 0; i < 2; ++i){
        int flat = i*256 + tid;
        int row = flat >> 3, cs = (flat & 7)*8;
        u16x8 val = *(const u16x8*)&sO[row*72 + cs];
        *(u16x8*)(ctx + (rowbase + row)*CC + h*64 + cs) = val;
    }
}

// ---------------- K3: out-projection, 128m x 64co tiles, LDS epilogue ----------------
__global__ __launch_bounds__(256) void out_gemm(const ushort* __restrict__ ctx,
                                                const ushort* __restrict__ Wob,
                                                const float* __restrict__ b_out,
                                                const float* __restrict__ x,
                                                const float* __restrict__ masks,
                                                float* __restrict__ out){
    __shared__ __align__(16) ushort smem[16896];   // staging 16K+8K, then f32 out tile
    ushort* sA = smem;            // 128*64
    ushort* sB = smem + 128*64;   // 64*64
    float* fOut = (float*)smem;   // [64 co][132] f32
    const int tid = threadIdx.x;
    const int bid = blockIdx.x;
    const int mtile  = ((bid & 7) << 4) | ((bid >> 3) & 15);
    const int cotile = bid >> 7;               // 0..7
    const int co0 = cotile * 64;
    const int m0  = mtile * 128;
    const int n = m0 >> 12, t0 = m0 & 4095;
    const ushort* Abase = ctx + (size_t)m0*CC;
    const ushort* Bbase = Wob + (size_t)co0*CC;
    const int w = tid >> 6, lane = tid & 63;
    const int wr = w >> 1, wc = w & 1;
    const int l15 = lane & 15, quad = lane >> 4;

    const ushort* gA[4]; ushort* lA[4];
    const ushort* gB[2]; ushort* lB[2];
    for (int i = 0; i < 4; ++i){
        int slot = i*256 + tid;
        int m = slot >> 3, k8 = slot & 7, kk = k8 ^ (m & 7);
        gA[i] = Abase + (size_t)m*CC + kk*8;
        lA[i] = sA + (i*256 + (tid & ~63)) * 8;
    }
    for (int i = 0; i < 2; ++i){
        int slot = i*256 + tid;
        int m = slot >> 3, k8 = slot & 7, kk = k8 ^ (m & 7);
        gB[i] = Bbase + (size_t)m*CC + kk*8;
        lB[i] = sB + (i*256 + (tid & ~63)) * 8;
    }

    f32x4 acc[4][2] = {};
    for (int kb = 0; kb < 8; ++kb){
        __syncthreads();
        for (int i = 0; i < 4; ++i) gload16(gA[i] + kb*64, lA[i]);
        for (int i = 0; i < 2; ++i) gload16(gB[i] + kb*64, lB[i]);
        __syncthreads();
        for (int ks = 0; ks < 2; ++ks){
            short8 aF[4], bF[2];
            for (int mi = 0; mi < 4; ++mi){
                int m = wr*64 + mi*16 + l15;
                aF[mi] = *(const short8*)&sA[(m*8 + ((ks*4 + quad) ^ (m & 7)))*8];
            }
            for (int ni = 0; ni < 2; ++ni){
                int m = wc*32 + ni*16 + l15;
                bF[ni] = *(const short8*)&sB[(m*8 + ((ks*4 + quad) ^ (m & 7)))*8];
            }
            for (int mi = 0; mi < 4; ++mi)
                for (int ni = 0; ni < 2; ++ni)
                    acc[mi][ni] = __builtin_amdgcn_mfma_f32_16x16x32_bf16(
                        aF[mi], bF[ni], acc[mi][ni], 0, 0, 0);
        }
    }
    float bo[2];
    for (int ni = 0; ni < 2; ++ni) bo[ni] = b_out[co0 + wc*32 + ni*16 + l15];

    __syncthreads();                 // staging done; reuse LDS as fOut[co][t]
    for (int mi = 0; mi < 4; ++mi){
        int tl = wr*64 + mi*16 + quad*4;
        for (int ni = 0; ni < 2; ++ni){
            int cl = wc*32 + ni*16 + l15;
            f32x4 vv;
            for (int r = 0; r < 4; ++r) vv[r] = acc[mi][ni][r] + bo[ni];
            *(f32x4*)&fOut[cl*132 + tl] = vv;
        }
    }
    __syncthreads();
    for (int i = 0; i < 8; ++i){
        int flat = i*256 + tid;
        int co = flat >> 5, ts = (flat & 31)*4;
        f32x4 a = *(const f32x4*)&fOut[co*132 + ts];
        f32x4 mk = *(const f32x4*)(masks + (size_t)n*TT + t0 + ts);
        f32x4 xv = *(const f32x4*)(x + ((size_t)n*CC + co0 + co)*TT + t0 + ts);
        f32x4 o;
        for (int r = 0; r < 4; ++r) o[r] = a[r]*mk[r] + xv[r];
        *(f32x4*)(out + ((size_t)n*CC + co0 + co)*TT + t0 + ts) = o;
    }
}

// ---------------- K4: InstanceNorm over T per (n,c), in place ----------------
__global__ __launch_bounds__(256) void inorm(float* __restrict__ out){
    __shared__ float sS[4], sQ2[4];
    float* row = out + (size_t)blockIdx.x * TT;
    f32x4 vbuf[4];
    float s = 0.f, ss = 0.f;
    for (int i = 0; i < 4; ++i){
        f32x4 vv = *(const f32x4*)(row + (size_t)(i*256 + threadIdx.x)*4);
        vbuf[i] = vv;
        for (int r = 0; r < 4; ++r){ s += vv[r]; ss += vv[r]*vv[r]; }
    }
    for (int d = 1; d < 64; d <<= 1){ s += __shfl_xor(s, d); ss += __shfl_xor(ss, d); }
    int w = threadIdx.x >> 6;
    if ((threadIdx.x & 63) == 0){ sS[w] = s; sQ2[w] = ss; }
    __syncthreads();
    s  = sS[0] + sS[1] + sS[2] + sS[3];
    ss = sQ2[0] + sQ2[1] + sQ2[2] + sQ2[3];
    float mean = s * (1.0f/TT);
    float var  = ss * (1.0f/TT) - mean*mean;
    float rstd = rsqrtf(var + 1e-5f);
    for (int i = 0; i < 4; ++i){
        f32x4 vv = vbuf[i], o;
        for (int r = 0; r < 4; ++r) o[r] = (vv[r] - mean) * rstd;
        *(f32x4*)(row + (size_t)(i*256 + threadIdx.x)*4) = o;
    }
}

extern "C" void kernel_launch(void* const* d_in, const int* in_sizes, int n_in,
                              void* d_out, int out_size, void* d_ws, size_t ws_size,
                              hipStream_t stream) {
    const float* x     = (const float*)d_in[0];
    const float* q     = (const float*)d_in[1];
    const float* k     = (const float*)d_in[2];
    const float* v     = (const float*)d_in[3];
    const float* masks = (const float*)d_in[4];
    const float* W_in  = (const float*)d_in[5];
    const float* b_in  = (const float*)d_in[6];
    const float* W_out = (const float*)d_in[7];
    const float* b_out = (const float*)d_in[8];
    float* out = (float*)d_out;

    ushort* ws  = (ushort*)d_ws;
    ushort* ctx = ws;                           // NTC bf16 (attention output)
    ushort* Wb  = ws + (size_t)NTC;             // 786432
    ushort* Wob = Wb + 786432;                  // 262144
    ushort* P   = Wob + 262144;                 // NB*TT*CQK (Q,K projected)
    ushort* Vt  = P + (size_t)NB*TT*CQK;        // NTC (V projected, transposed)

    wcvt<<<256, 256, 0, stream>>>(W_in, W_out, Wb, Wob);
    proj_gemm<<<1536, 256, 0, stream>>>(q, k, v, Wb, b_in, P, Vt);
    attn_kernel<<<2048, 256, 0, stream>>>(P, Vt, masks, ctx);
    out_gemm<<<1024, 256, 0, stream>>>(ctx, Wob, b_out, x, masks, out);
    inorm<<<2048, 256, 0, stream>>>(out);
}

// Round 7
// 244.406 us; speedup vs baseline: 1.1011x; 1.0030x over previous
//
#include <hip/hip_runtime.h>
#include <hip/hip_bf16.h>

#define NB 4
#define CC 512
#define TT 4096
#define C3 1536
#define CQK 1024
#define NTC (NB*TT*CC)   // 8388608 elems per [N,T,C] tensor

typedef __attribute__((ext_vector_type(4))) float f32x4;
typedef __attribute__((ext_vector_type(8))) short short8;
typedef unsigned short ushort;
typedef __attribute__((ext_vector_type(8))) ushort u16x8;

__device__ __forceinline__ ushort f2bf(float f){
    union { float f; unsigned u; } x; x.f = f;
    unsigned r = x.u + 0x7fffu + ((x.u >> 16) & 1u);   // RNE
    return (ushort)(r >> 16);
}

__device__ __forceinline__ ushort2 pk2bf(float a, float b){
    float2 f2; f2.x = a; f2.y = b;
    __hip_bfloat162 h = __float22bfloat162_rn(f2);     // v_cvt_pk_bf16_f32 (RNE)
    union { __hip_bfloat162 h2; ushort2 u2; } u; u.h2 = h;
    return u.u2;
}

__device__ __forceinline__ void gload16(const void* g, void* l){
    __builtin_amdgcn_global_load_lds((const __attribute__((address_space(1))) void*)g,
                                     (__attribute__((address_space(3))) void*)l,
                                     16, 0, 0);
}

// sA swizzle: 16B slot position for logical c-block cb at row m.
__device__ __forceinline__ int apos(int m, int cb){
    return (m*8 + ((cb + m + (m >> 3)) & 7))*8;
}

// ---------------- K0: weight fp32 -> bf16 ----------------
__global__ __launch_bounds__(256) void wcvt(const float* __restrict__ Wi,
                                            const float* __restrict__ Wo,
                                            ushort* __restrict__ Wb,
                                            ushort* __restrict__ Wob){
    int idx0 = blockIdx.x * 1024 + threadIdx.x;
    for (int i = 0; i < 4; ++i){
        int idx = idx0 + i*256;
        const float* src; ushort* dst; int j;
        if (idx < 196608){ src = Wi; dst = Wb;  j = idx; }
        else             { src = Wo; dst = Wob; j = idx - 196608; }
        f32x4 vv = *((const f32x4*)src + j);
        ushort4 o;
        *(ushort2*)&o.x = pk2bf(vv[0], vv[1]);
        *(ushort2*)&o.z = pk2bf(vv[2], vv[3]);
        *((ushort4*)dst + j) = o;
    }
}

// ---------------- K1: fused transpose+cvt + QKV projection GEMM ----------------
// A read directly from q/k/v fp32 [N,C,T] with 1-iteration register prefetch;
// micro-transpose -> sA (bf16). B staged via global_load_lds.
__global__ __launch_bounds__(256) void proj_gemm(const float* __restrict__ q,
                                                 const float* __restrict__ k,
                                                 const float* __restrict__ v,
                                                 const ushort* __restrict__ Wb,
                                                 const float* __restrict__ b_in,
                                                 ushort* __restrict__ P,
                                                 ushort* __restrict__ Vt){
    __shared__ __align__(16) ushort smem[128*136];   // sA 16K + sB 16K, then sOut[128][136]
    ushort* sA = smem;            // 128 rows x 8 slots x 8 ushorts
    ushort* sB = smem + 128*64;
    const int tid = threadIdx.x;
    const int bid = blockIdx.x;
    const int mtile  = ((bid & 7) << 4) | ((bid >> 3) & 15);
    const int cotile = bid >> 7;               // 0..11
    const int co0 = cotile * 128;
    const int m0  = mtile * 128;
    const int which = co0 >> 9;                // 0:q 1:k 2:v
    const float* src = (which == 0) ? q : (which == 1) ? k : v;
    const int n  = m0 >> 12, t0 = m0 & 4095;
    const ushort* Bbase = Wb + (size_t)co0*CC;
    const int w = tid >> 6, lane = tid & 63;
    const int wr = w >> 1, wc = w & 1;
    const int l15 = lane & 15, quad = lane >> 4;

    // A staging: wave w covers c-rows [w*16, w*16+16), cb = 2w + (lane>>5), t = (lane&31)*4+tj
    const int cbA = (w << 1) | (lane >> 5);
    const int tA  = lane & 31;
    const float* Abase = src + (size_t)n*CC*TT + (size_t)(cbA*8)*TT + t0 + tA*4;

    const ushort* gB[4]; ushort* lB[4];
    for (int i = 0; i < 4; ++i){
        int slot = i*256 + tid;
        int mr = slot >> 3, k8 = slot & 7, kk = k8 ^ (mr & 7);
        gB[i] = Bbase + (size_t)mr*CC + kk*8;
        lB[i] = sB + (i*256 + (tid & ~63)) * 8;
    }

    f32x4 acc[4][4] = {};
    f32x4 cur[8], nxt[8];
    #pragma unroll
    for (int j = 0; j < 8; ++j)
        cur[j] = *(const f32x4*)(Abase + (size_t)j*TT);

    for (int kb = 0; kb < 8; ++kb){
        __syncthreads();
        #pragma unroll
        for (int tj = 0; tj < 4; ++tj){
            int m = tA*4 + tj;
            u16x8 o;
            #pragma unroll
            for (int j = 0; j < 8; j += 2){
                ushort2 p = pk2bf(cur[j][tj], cur[j+1][tj]);
                o[j] = p.x; o[j+1] = p.y;
            }
            *(u16x8*)&sA[apos(m, cbA)] = o;
        }
        for (int i = 0; i < 4; ++i) gload16(gB[i] + kb*64, lB[i]);
        __syncthreads();
        // prefetch next A tile AFTER the barrier (so its vmcnt(0) drain
        // doesn't kill the prefetch); covered by the MFMA block below.
        if (kb < 7){
            const float* Ab = Abase + (size_t)((kb+1)*64)*TT;
            #pragma unroll
            for (int j = 0; j < 8; ++j)
                nxt[j] = *(const f32x4*)(Ab + (size_t)j*TT);
        }
        for (int ks = 0; ks < 2; ++ks){
            short8 aF[4], bF[4];
            for (int mi = 0; mi < 4; ++mi){
                int m = wr*64 + mi*16 + l15;
                aF[mi] = *(const short8*)&sA[apos(m, ks*4 + quad)];
            }
            for (int ni = 0; ni < 4; ++ni){
                int m = wc*64 + ni*16 + l15;
                bF[ni] = *(const short8*)&sB[(m*8 + ((ks*4 + quad) ^ (m & 7)))*8];
            }
            for (int mi = 0; mi < 4; ++mi)
                for (int ni = 0; ni < 4; ++ni)
                    acc[mi][ni] = __builtin_amdgcn_mfma_f32_16x16x32_bf16(
                        aF[mi], bF[ni], acc[mi][ni], 0, 0, 0);
        }
        if (kb < 7){
            #pragma unroll
            for (int j = 0; j < 8; ++j) cur[j] = nxt[j];
        }
    }

    float bj[4];
    for (int ni = 0; ni < 4; ++ni) bj[ni] = b_in[co0 + wc*64 + ni*16 + l15];

    __syncthreads();                 // done with sA/sB; reuse as sOut[128][136]
    ushort* sOut = smem;
    if (which < 2){
        for (int mi = 0; mi < 4; ++mi){
            int mrow = wr*64 + mi*16 + quad*4;
            for (int ni = 0; ni < 4; ++ni){
                int col = wc*64 + ni*16 + l15;
                for (int r = 0; r < 4; ++r)
                    sOut[(mrow + r)*136 + col] = f2bf(acc[mi][ni][r] + bj[ni]);
            }
        }
    } else {
        for (int mi = 0; mi < 4; ++mi){
            int mrow = wr*64 + mi*16 + quad*4;
            for (int ni = 0; ni < 4; ++ni){
                int col = wc*64 + ni*16 + l15;
                ushort4 o4;
                o4.x = f2bf(acc[mi][ni][0] + bj[ni]);
                o4.y = f2bf(acc[mi][ni][1] + bj[ni]);
                o4.z = f2bf(acc[mi][ni][2] + bj[ni]);
                o4.w = f2bf(acc[mi][ni][3] + bj[ni]);
                *(ushort4*)&sOut[col*136 + mrow] = o4;   // mrow%4==0, contiguous
            }
        }
    }
    __syncthreads();
    if (which < 2){
        for (int i = 0; i < 8; ++i){
            int flat = i*256 + tid;
            int row = flat >> 4, cs = (flat & 15)*8;
            u16x8 val = *(const u16x8*)&sOut[row*136 + cs];
            *(u16x8*)(P + (size_t)(m0 + row)*CQK + which*512 + (co0 & 511) + cs) = val;
        }
    } else {
        for (int i = 0; i < 8; ++i){
            int flat = i*256 + tid;
            int row = flat >> 4, cs = (flat & 15)*8;    // row = local co (d), cs along t
            int cl = (co0 - 1024) + row;
            int h = cl >> 6, d = cl & 63;
            u16x8 val = *(const u16x8*)&sOut[row*136 + cs];
            *(u16x8*)(Vt + (((size_t)n*8 + h)*64 + d)*TT + t0 + cs) = val;
        }
    }
}

// ---------------- K2: per-(n,chunk,head) attention (LDS epilogue) ----------------
__global__ __launch_bounds__(256) void attn_kernel(const ushort* __restrict__ P,
                                                   const ushort* __restrict__ Vt,
                                                   const float* __restrict__ masks,
                                                   ushort* __restrict__ ctx){
    __shared__ __align__(16) ushort sQ[64*64], sK[64*64], sV[64*64];   // swizzled
    __shared__ __align__(16) ushort sP[64][72];
    __shared__ __align__(16) ushort sO[64*72];
    int bid = blockIdx.x;
    int h = bid & 7, ch = (bid >> 3) & 63, n = bid >> 9;
    const int tid = threadIdx.x, lane = tid & 63, w = tid >> 6;
    const int l15 = lane & 15, quad = lane >> 4;
    const size_t rowbase = (size_t)n*TT + (size_t)ch*64;
    for (int i = 0; i < 2; ++i){
        int slot = i*256 + tid;
        int r = slot >> 3, k8 = slot & 7, kk = k8 ^ (r & 7);
        int lbase = (i*256 + (tid & ~63)) * 8;
        const ushort* gq = P + (rowbase + r)*CQK + h*64 + kk*8;
        gload16(gq,        sQ + lbase);
        gload16(gq + 512,  sK + lbase);
        const ushort* gv = Vt + (((size_t)n*8 + h)*64 + r)*TT + ch*64 + kk*8;
        gload16(gv,        sV + lbase);
    }
    __syncthreads();
    const int m0w = w*16;
    short8 aQ[2]; f32x4 accS[4] = {};
    for (int ks = 0; ks < 2; ++ks){
        int m = m0w + l15;
        aQ[ks] = *(const short8*)&sQ[(m*8 + ((ks*4 + quad) ^ (m & 7)))*8];
    }
    for (int ni = 0; ni < 4; ++ni)
        for (int ks = 0; ks < 2; ++ks){
            int m = ni*16 + l15;
            short8 bK = *(const short8*)&sK[(m*8 + ((ks*4 + quad) ^ (m & 7)))*8];
            accS[ni] = __builtin_amdgcn_mfma_f32_16x16x32_bf16(aQ[ks], bK, accS[ni], 0,0,0);
        }
    float madd[4];
    for (int ni = 0; ni < 4; ++ni){
        float mv = masks[(size_t)n*TT + ch*64 + ni*16 + l15];
        madd[ni] = (mv > 0.f) ? 0.f : -1e9f;
    }
    float s[4][4];
    for (int ni = 0; ni < 4; ++ni)
        for (int r = 0; r < 4; ++r) s[ni][r] = accS[ni][r]*0.125f + madd[ni];
    float ex[4][4];
    for (int r = 0; r < 4; ++r){
        float m1 = fmaxf(fmaxf(s[0][r], s[1][r]), fmaxf(s[2][r], s[3][r]));
        for (int d = 1; d < 16; d <<= 1) m1 = fmaxf(m1, __shfl_xor(m1, d));
        float a = 0.f;
        for (int ni = 0; ni < 4; ++ni){ float e = __expf(s[ni][r] - m1); ex[ni][r] = e; a += e; }
        for (int d = 1; d < 16; d <<= 1) a += __shfl_xor(a, d);
        float rs = 1.0f / a;
        for (int ni = 0; ni < 4; ++ni)
            sP[m0w + quad*4 + r][ni*16 + l15] = f2bf(ex[ni][r] * rs);
    }
    short8 aP[2]; f32x4 accO[4] = {};
    for (int ks = 0; ks < 2; ++ks)
        aP[ks] = *(const short8*)&sP[m0w + l15][ks*32 + quad*8];
    for (int ni = 0; ni < 4; ++ni)
        for (int ks = 0; ks < 2; ++ks){
            int m = ni*16 + l15;
            short8 bV = *(const short8*)&sV[(m*8 + ((ks*4 + quad) ^ (m & 7)))*8];
            accO[ni] = __builtin_amdgcn_mfma_f32_16x16x32_bf16(aP[ks], bV, accO[ni], 0,0,0);
        }
    for (int ni = 0; ni < 4; ++ni)
        for (int r = 0; r < 4; ++r)
            sO[(m0w + quad*4 + r)*72 + ni*16 + l15] = f2bf(accO[ni][r]);
    __syncthreads();
    for (int i = 0; i < 2; ++i){
        int flat = i*256 + tid;
        int row = flat >> 3, cs = (flat & 7)*8;
        u16x8 val = *(const u16x8*)&sO[row*72 + cs];
        *(u16x8*)(ctx + (rowbase + row)*CC + h*64 + cs) = val;
    }
}

// ---------------- K3: out-projection, 128m x 64co tiles, LDS epilogue ----------------
__global__ __launch_bounds__(256) void out_gemm(const ushort* __restrict__ ctx,
                                                const ushort* __restrict__ Wob,
                                                const float* __restrict__ b_out,
                                                const float* __restrict__ x,
                                                const float* __restrict__ masks,
                                                float* __restrict__ out){
    __shared__ __align__(16) ushort smem[16896];   // staging 16K+8K, then f32 out tile
    ushort* sA = smem;            // 128*64
    ushort* sB = smem + 128*64;   // 64*64
    float* fOut = (float*)smem;   // [64 co][132] f32
    const int tid = threadIdx.x;
    const int bid = blockIdx.x;
    const int mtile  = ((bid & 7) << 4) | ((bid >> 3) & 15);
    const int cotile = bid >> 7;               // 0..7
    const int co0 = cotile * 64;
    const int m0  = mtile * 128;
    const int n = m0 >> 12, t0 = m0 & 4095;
    const ushort* Abase = ctx + (size_t)m0*CC;
    const ushort* Bbase = Wob + (size_t)co0*CC;
    const int w = tid >> 6, lane = tid & 63;
    const int wr = w >> 1, wc = w & 1;
    const int l15 = lane & 15, quad = lane >> 4;

    const ushort* gA[4]; ushort* lA[4];
    const ushort* gB[2]; ushort* lB[2];
    for (int i = 0; i < 4; ++i){
        int slot = i*256 + tid;
        int m = slot >> 3, k8 = slot & 7, kk = k8 ^ (m & 7);
        gA[i] = Abase + (size_t)m*CC + kk*8;
        lA[i] = sA + (i*256 + (tid & ~63)) * 8;
    }
    for (int i = 0; i < 2; ++i){
        int slot = i*256 + tid;
        int m = slot >> 3, k8 = slot & 7, kk = k8 ^ (m & 7);
        gB[i] = Bbase + (size_t)m*CC + kk*8;
        lB[i] = sB + (i*256 + (tid & ~63)) * 8;
    }

    f32x4 acc[4][2] = {};
    for (int kb = 0; kb < 8; ++kb){
        __syncthreads();
        for (int i = 0; i < 4; ++i) gload16(gA[i] + kb*64, lA[i]);
        for (int i = 0; i < 2; ++i) gload16(gB[i] + kb*64, lB[i]);
        __syncthreads();
        for (int ks = 0; ks < 2; ++ks){
            short8 aF[4], bF[2];
            for (int mi = 0; mi < 4; ++mi){
                int m = wr*64 + mi*16 + l15;
                aF[mi] = *(const short8*)&sA[(m*8 + ((ks*4 + quad) ^ (m & 7)))*8];
            }
            for (int ni = 0; ni < 2; ++ni){
                int m = wc*32 + ni*16 + l15;
                bF[ni] = *(const short8*)&sB[(m*8 + ((ks*4 + quad) ^ (m & 7)))*8];
            }
            for (int mi = 0; mi < 4; ++mi)
                for (int ni = 0; ni < 2; ++ni)
                    acc[mi][ni] = __builtin_amdgcn_mfma_f32_16x16x32_bf16(
                        aF[mi], bF[ni], acc[mi][ni], 0, 0, 0);
        }
    }
    float bo[2];
    for (int ni = 0; ni < 2; ++ni) bo[ni] = b_out[co0 + wc*32 + ni*16 + l15];

    __syncthreads();                 // staging done; reuse LDS as fOut[co][t]
    for (int mi = 0; mi < 4; ++mi){
        int tl = wr*64 + mi*16 + quad*4;
        for (int ni = 0; ni < 2; ++ni){
            int cl = wc*32 + ni*16 + l15;
            f32x4 vv;
            for (int r = 0; r < 4; ++r) vv[r] = acc[mi][ni][r] + bo[ni];
            *(f32x4*)&fOut[cl*132 + tl] = vv;
        }
    }
    __syncthreads();
    for (int i = 0; i < 8; ++i){
        int flat = i*256 + tid;
        int co = flat >> 5, ts = (flat & 31)*4;
        f32x4 a = *(const f32x4*)&fOut[co*132 + ts];
        f32x4 mk = *(const f32x4*)(masks + (size_t)n*TT + t0 + ts);
        f32x4 xv = *(const f32x4*)(x + ((size_t)n*CC + co0 + co)*TT + t0 + ts);
        f32x4 o;
        for (int r = 0; r < 4; ++r) o[r] = a[r]*mk[r] + xv[r];
        *(f32x4*)(out + ((size_t)n*CC + co0 + co)*TT + t0 + ts) = o;
    }
}

// ---------------- K4: InstanceNorm over T per (n,c), in place ----------------
__global__ __launch_bounds__(256) void inorm(float* __restrict__ out){
    __shared__ float sS[4], sQ2[4];
    float* row = out + (size_t)blockIdx.x * TT;
    f32x4 vbuf[4];
    float s = 0.f, ss = 0.f;
    for (int i = 0; i < 4; ++i){
        f32x4 vv = *(const f32x4*)(row + (size_t)(i*256 + threadIdx.x)*4);
        vbuf[i] = vv;
        for (int r = 0; r < 4; ++r){ s += vv[r]; ss += vv[r]*vv[r]; }
    }
    for (int d = 1; d < 64; d <<= 1){ s += __shfl_xor(s, d); ss += __shfl_xor(ss, d); }
    int w = threadIdx.x >> 6;
    if ((threadIdx.x & 63) == 0){ sS[w] = s; sQ2[w] = ss; }
    __syncthreads();
    s  = sS[0] + sS[1] + sS[2] + sS[3];
    ss = sQ2[0] + sQ2[1] + sQ2[2] + sQ2[3];
    float mean = s * (1.0f/TT);
    float var  = ss * (1.0f/TT) - mean*mean;
    float rstd = rsqrtf(var + 1e-5f);
    for (int i = 0; i < 4; ++i){
        f32x4 vv = vbuf[i], o;
        for (int r = 0; r < 4; ++r) o[r] = (vv[r] - mean) * rstd;
        *(f32x4*)(row + (size_t)(i*256 + threadIdx.x)*4) = o;
    }
}

extern "C" void kernel_launch(void* const* d_in, const int* in_sizes, int n_in,
                              void* d_out, int out_size, void* d_ws, size_t ws_size,
                              hipStream_t stream) {
    const float* x     = (const float*)d_in[0];
    const float* q     = (const float*)d_in[1];
    const float* k     = (const float*)d_in[2];
    const float* v     = (const float*)d_in[3];
    const float* masks = (const float*)d_in[4];
    const float* W_in  = (const float*)d_in[5];
    const float* b_in  = (const float*)d_in[6];
    const float* W_out = (const float*)d_in[7];
    const float* b_out = (const float*)d_in[8];
    float* out = (float*)d_out;

    ushort* ws  = (ushort*)d_ws;
    ushort* ctx = ws;                           // NTC bf16 (attention output)
    ushort* Wb  = ws + (size_t)NTC;             // 786432
    ushort* Wob = Wb + 786432;                  // 262144
    ushort* P   = Wob + 262144;                 // NB*TT*CQK (Q,K projected)
    ushort* Vt  = P + (size_t)NB*TT*CQK;        // NTC (V projected, transposed)

    wcvt<<<256, 256, 0, stream>>>(W_in, W_out, Wb, Wob);
    proj_gemm<<<1536, 256, 0, stream>>>(q, k, v, Wb, b_in, P, Vt);
    attn_kernel<<<2048, 256, 0, stream>>>(P, Vt, masks, ctx);
    out_gemm<<<1024, 256, 0, stream>>>(ctx, Wob, b_out, x, masks, out);
    inorm<<<2048, 256, 0, stream>>>(out);
}

// Round 8
// 239.908 us; speedup vs baseline: 1.1218x; 1.0187x over previous
//
#include <hip/hip_runtime.h>
#include <hip/hip_bf16.h>

#define NB 4
#define CC 512
#define TT 4096
#define C3 1536
#define CQK 1024
#define NTC (NB*TT*CC)   // 8388608 elems per [N,T,C] tensor

typedef __attribute__((ext_vector_type(4))) float f32x4;
typedef __attribute__((ext_vector_type(8))) short short8;
typedef unsigned short ushort;
typedef __attribute__((ext_vector_type(8))) ushort u16x8;

__device__ __forceinline__ ushort f2bf(float f){
    union { float f; unsigned u; } x; x.f = f;
    unsigned r = x.u + 0x7fffu + ((x.u >> 16) & 1u);   // RNE
    return (ushort)(r >> 16);
}

__device__ __forceinline__ ushort2 pk2bf(float a, float b){
    float2 f2; f2.x = a; f2.y = b;
    __hip_bfloat162 h = __float22bfloat162_rn(f2);     // v_cvt_pk_bf16_f32 (RNE)
    union { __hip_bfloat162 h2; ushort2 u2; } u; u.h2 = h;
    return u.u2;
}

__device__ __forceinline__ void gload16(const void* g, void* l){
    __builtin_amdgcn_global_load_lds((const __attribute__((address_space(1))) void*)g,
                                     (__attribute__((address_space(3))) void*)l,
                                     16, 0, 0);
}

// sA swizzle: 16B slot position for logical c-block cb at row m.
__device__ __forceinline__ int apos(int m, int cb){
    return (m*8 + ((cb + m + (m >> 3)) & 7))*8;
}

// ---------------- K0: weight fp32 -> bf16 ----------------
__global__ __launch_bounds__(256) void wcvt(const float* __restrict__ Wi,
                                            const float* __restrict__ Wo,
                                            ushort* __restrict__ Wb,
                                            ushort* __restrict__ Wob){
    int idx0 = blockIdx.x * 1024 + threadIdx.x;
    for (int i = 0; i < 4; ++i){
        int idx = idx0 + i*256;
        const float* src; ushort* dst; int j;
        if (idx < 196608){ src = Wi; dst = Wb;  j = idx; }
        else             { src = Wo; dst = Wob; j = idx - 196608; }
        f32x4 vv = *((const f32x4*)src + j);
        ushort4 o;
        *(ushort2*)&o.x = pk2bf(vv[0], vv[1]);
        *(ushort2*)&o.z = pk2bf(vv[2], vv[3]);
        *((ushort4*)dst + j) = o;
    }
}

// ---------------- K1: fused transpose+cvt + QKV projection GEMM ----------------
// fp32 A-tile staged async into LDS (Araw, contiguous rows); transpose+cvt is
// LDS->reg->LDS. B double-buffered async. One kb of latency covered by MFMA.
__global__ __launch_bounds__(256) void proj_gemm(const float* __restrict__ q,
                                                 const float* __restrict__ k,
                                                 const float* __restrict__ v,
                                                 const ushort* __restrict__ Wb,
                                                 const float* __restrict__ b_in,
                                                 ushort* __restrict__ P,
                                                 ushort* __restrict__ Vt){
    __shared__ __align__(16) ushort smem[40960];   // 80 KB
    ushort* sA   = smem;                    // 16 KB  (bf16 A, swizzled)
    ushort* sB0  = smem + 8192;             // 16 KB
    ushort* sB1  = smem + 16384;            // 16 KB
    float*  Araw = (float*)(smem + 24576);  // 32 KB  (fp32 A tile, 64 c-rows x 128 t)
    const int tid = threadIdx.x;
    const int bid = blockIdx.x;
    const int mtile  = ((bid & 7) << 4) | ((bid >> 3) & 15);
    const int cotile = bid >> 7;               // 0..11
    const int co0 = cotile * 128;
    const int m0  = mtile * 128;
    const int which = co0 >> 9;                // 0:q 1:k 2:v
    const float* src = (which == 0) ? q : (which == 1) ? k : v;
    const int n  = m0 >> 12, t0 = m0 & 4095;
    const ushort* Bbase = Wb + (size_t)co0*CC;
    const int w = tid >> 6, lane = tid & 63;
    const int wr = w >> 1, wc = w & 1;
    const int l15 = lane & 15, quad = lane >> 4;

    // ---- A async staging: wave w, round r loads c-rows {r*8+2w, r*8+2w+1} ----
    const int rowoff = lane >> 5;            // 0/1
    const int toff   = (lane & 31) * 4;      // float offset within row
    const float* Ag = src + (size_t)n*CC*TT + (size_t)(2*w + rowoff)*TT + t0 + toff;
    float* lAr = Araw + (size_t)(2*w)*128;   // wave-uniform dest base

    // ---- B async staging slots ----
    const ushort* gB[4]; int lBoff[4];
    for (int i = 0; i < 4; ++i){
        int slot = i*256 + tid;
        int mr = slot >> 3, k8 = slot & 7, kk = k8 ^ (mr & 7);
        gB[i] = Bbase + (size_t)mr*CC + kk*8;
        lBoff[i] = (i*256 + (tid & ~63)) * 8;
    }

    // ---- transpose-read mapping ----
    const int cbA = (w << 1) | (lane >> 5);  // 0..7 c-block
    const int tA  = lane & 31;               // t-group of 4

    // prologue: issue kb=0 tiles
    for (int r = 0; r < 8; ++r)
        gload16(Ag + (size_t)(r*8)*TT, lAr + r*1024);
    for (int i = 0; i < 4; ++i)
        gload16(gB[i], sB0 + lBoff[i]);

    f32x4 acc[4][4] = {};
    for (int kb = 0; kb < 8; ++kb){
        ushort* sBc = (kb & 1) ? sB1 : sB0;
        ushort* sBn = (kb & 1) ? sB0 : sB1;
        __syncthreads();       // B1: asyncs for kb landed; prior MFMA reads done
        // transpose Araw (fp32) -> sA (bf16)
        f32x4 cur[8];
        #pragma unroll
        for (int j = 0; j < 8; ++j)
            cur[j] = *(const f32x4*)(Araw + (size_t)(cbA*8 + j)*128 + tA*4);
        #pragma unroll
        for (int tj = 0; tj < 4; ++tj){
            int m = tA*4 + tj;
            u16x8 o;
            #pragma unroll
            for (int j = 0; j < 8; j += 2){
                ushort2 p = pk2bf(cur[j][tj], cur[j+1][tj]);
                o[j] = p.x; o[j+1] = p.y;
            }
            *(u16x8*)&sA[apos(m, cbA)] = o;
        }
        __syncthreads();       // B2: sA visible; Araw fully consumed
        if (kb < 7){           // issue kb+1 asyncs; covered by MFMA below
            const float* Agn = Ag + (size_t)((kb+1)*64)*TT;
            for (int r = 0; r < 8; ++r)
                gload16(Agn + (size_t)(r*8)*TT, lAr + r*1024);
            for (int i = 0; i < 4; ++i)
                gload16(gB[i] + (kb+1)*64, sBn + lBoff[i]);
        }
        for (int ks = 0; ks < 2; ++ks){
            short8 aF[4], bF[4];
            for (int mi = 0; mi < 4; ++mi){
                int m = wr*64 + mi*16 + l15;
                aF[mi] = *(const short8*)&sA[apos(m, ks*4 + quad)];
            }
            for (int ni = 0; ni < 4; ++ni){
                int m = wc*64 + ni*16 + l15;
                bF[ni] = *(const short8*)&sBc[(m*8 + ((ks*4 + quad) ^ (m & 7)))*8];
            }
            for (int mi = 0; mi < 4; ++mi)
                for (int ni = 0; ni < 4; ++ni)
                    acc[mi][ni] = __builtin_amdgcn_mfma_f32_16x16x32_bf16(
                        aF[mi], bF[ni], acc[mi][ni], 0, 0, 0);
        }
    }

    float bj[4];
    for (int ni = 0; ni < 4; ++ni) bj[ni] = b_in[co0 + wc*64 + ni*16 + l15];

    __syncthreads();                 // done with staging; reuse as sOut[128][136]
    ushort* sOut = smem;
    if (which < 2){
        for (int mi = 0; mi < 4; ++mi){
            int mrow = wr*64 + mi*16 + quad*4;
            for (int ni = 0; ni < 4; ++ni){
                int col = wc*64 + ni*16 + l15;
                for (int r = 0; r < 4; ++r)
                    sOut[(mrow + r)*136 + col] = f2bf(acc[mi][ni][r] + bj[ni]);
            }
        }
    } else {
        for (int mi = 0; mi < 4; ++mi){
            int mrow = wr*64 + mi*16 + quad*4;
            for (int ni = 0; ni < 4; ++ni){
                int col = wc*64 + ni*16 + l15;
                ushort4 o4;
                o4.x = f2bf(acc[mi][ni][0] + bj[ni]);
                o4.y = f2bf(acc[mi][ni][1] + bj[ni]);
                o4.z = f2bf(acc[mi][ni][2] + bj[ni]);
                o4.w = f2bf(acc[mi][ni][3] + bj[ni]);
                *(ushort4*)&sOut[col*136 + mrow] = o4;   // mrow%4==0, contiguous
            }
        }
    }
    __syncthreads();
    if (which < 2){
        for (int i = 0; i < 8; ++i){
            int flat = i*256 + tid;
            int row = flat >> 4, cs = (flat & 15)*8;
            u16x8 val = *(const u16x8*)&sOut[row*136 + cs];
            *(u16x8*)(P + (size_t)(m0 + row)*CQK + which*512 + (co0 & 511) + cs) = val;
        }
    } else {
        for (int i = 0; i < 8; ++i){
            int flat = i*256 + tid;
            int row = flat >> 4, cs = (flat & 15)*8;    // row = local co (d), cs along t
            int cl = (co0 - 1024) + row;
            int h = cl >> 6, d = cl & 63;
            u16x8 val = *(const u16x8*)&sOut[row*136 + cs];
            *(u16x8*)(Vt + (((size_t)n*8 + h)*64 + d)*TT + t0 + cs) = val;
        }
    }
}

// ---------------- K2: per-(n,chunk,head) attention (LDS epilogue) ----------------
__global__ __launch_bounds__(256) void attn_kernel(const ushort* __restrict__ P,
                                                   const ushort* __restrict__ Vt,
                                                   const float* __restrict__ masks,
                                                   ushort* __restrict__ ctx){
    __shared__ __align__(16) ushort sQ[64*64], sK[64*64], sV[64*64];   // swizzled
    __shared__ __align__(16) ushort sP[64][72];
    __shared__ __align__(16) ushort sO[64*72];
    int bid = blockIdx.x;
    int h = bid & 7, ch = (bid >> 3) & 63, n = bid >> 9;
    const int tid = threadIdx.x, lane = tid & 63, w = tid >> 6;
    const int l15 = lane & 15, quad = lane >> 4;
    const size_t rowbase = (size_t)n*TT + (size_t)ch*64;
    for (int i = 0; i < 2; ++i){
        int slot = i*256 + tid;
        int r = slot >> 3, k8 = slot & 7, kk = k8 ^ (r & 7);
        int lbase = (i*256 + (tid & ~63)) * 8;
        const ushort* gq = P + (rowbase + r)*CQK + h*64 + kk*8;
        gload16(gq,        sQ + lbase);
        gload16(gq + 512,  sK + lbase);
        const ushort* gv = Vt + (((size_t)n*8 + h)*64 + r)*TT + ch*64 + kk*8;
        gload16(gv,        sV + lbase);
    }
    __syncthreads();
    const int m0w = w*16;
    short8 aQ[2]; f32x4 accS[4] = {};
    for (int ks = 0; ks < 2; ++ks){
        int m = m0w + l15;
        aQ[ks] = *(const short8*)&sQ[(m*8 + ((ks*4 + quad) ^ (m & 7)))*8];
    }
    for (int ni = 0; ni < 4; ++ni)
        for (int ks = 0; ks < 2; ++ks){
            int m = ni*16 + l15;
            short8 bK = *(const short8*)&sK[(m*8 + ((ks*4 + quad) ^ (m & 7)))*8];
            accS[ni] = __builtin_amdgcn_mfma_f32_16x16x32_bf16(aQ[ks], bK, accS[ni], 0,0,0);
        }
    float madd[4];
    for (int ni = 0; ni < 4; ++ni){
        float mv = masks[(size_t)n*TT + ch*64 + ni*16 + l15];
        madd[ni] = (mv > 0.f) ? 0.f : -1e9f;
    }
    float s[4][4];
    for (int ni = 0; ni < 4; ++ni)
        for (int r = 0; r < 4; ++r) s[ni][r] = accS[ni][r]*0.125f + madd[ni];
    float ex[4][4];
    for (int r = 0; r < 4; ++r){
        float m1 = fmaxf(fmaxf(s[0][r], s[1][r]), fmaxf(s[2][r], s[3][r]));
        for (int d = 1; d < 16; d <<= 1) m1 = fmaxf(m1, __shfl_xor(m1, d));
        float a = 0.f;
        for (int ni = 0; ni < 4; ++ni){ float e = __expf(s[ni][r] - m1); ex[ni][r] = e; a += e; }
        for (int d = 1; d < 16; d <<= 1) a += __shfl_xor(a, d);
        float rs = 1.0f / a;
        for (int ni = 0; ni < 4; ++ni)
            sP[m0w + quad*4 + r][ni*16 + l15] = f2bf(ex[ni][r] * rs);
    }
    short8 aP[2]; f32x4 accO[4] = {};
    for (int ks = 0; ks < 2; ++ks)
        aP[ks] = *(const short8*)&sP[m0w + l15][ks*32 + quad*8];
    for (int ni = 0; ni < 4; ++ni)
        for (int ks = 0; ks < 2; ++ks){
            int m = ni*16 + l15;
            short8 bV = *(const short8*)&sV[(m*8 + ((ks*4 + quad) ^ (m & 7)))*8];
            accO[ni] = __builtin_amdgcn_mfma_f32_16x16x32_bf16(aP[ks], bV, accO[ni], 0,0,0);
        }
    for (int ni = 0; ni < 4; ++ni)
        for (int r = 0; r < 4; ++r)
            sO[(m0w + quad*4 + r)*72 + ni*16 + l15] = f2bf(accO[ni][r]);
    __syncthreads();
    for (int i = 0; i < 2; ++i){
        int flat = i*256 + tid;
        int row = flat >> 3, cs = (flat & 7)*8;
        u16x8 val = *(const u16x8*)&sO[row*72 + cs];
        *(u16x8*)(ctx + (rowbase + row)*CC + h*64 + cs) = val;
    }
}

// ---------------- K3: out-projection, 128m x 64co tiles, LDS epilogue ----------------
__global__ __launch_bounds__(256) void out_gemm(const ushort* __restrict__ ctx,
                                                const ushort* __restrict__ Wob,
                                                const float* __restrict__ b_out,
                                                const float* __restrict__ x,
                                                const float* __restrict__ masks,
                                                float* __restrict__ out){
    __shared__ __align__(16) ushort smem[16896];   // staging 16K+8K, then f32 out tile
    ushort* sA = smem;            // 128*64
    ushort* sB = smem + 128*64;   // 64*64
    float* fOut = (float*)smem;   // [64 co][132] f32
    const int tid = threadIdx.x;
    const int bid = blockIdx.x;
    const int mtile  = ((bid & 7) << 4) | ((bid >> 3) & 15);
    const int cotile = bid >> 7;               // 0..7
    const int co0 = cotile * 64;
    const int m0  = mtile * 128;
    const int n = m0 >> 12, t0 = m0 & 4095;
    const ushort* Abase = ctx + (size_t)m0*CC;
    const ushort* Bbase = Wob + (size_t)co0*CC;
    const int w = tid >> 6, lane = tid & 63;
    const int wr = w >> 1, wc = w & 1;
    const int l15 = lane & 15, quad = lane >> 4;

    const ushort* gA[4]; ushort* lA[4];
    const ushort* gB[2]; ushort* lB[2];
    for (int i = 0; i < 4; ++i){
        int slot = i*256 + tid;
        int m = slot >> 3, k8 = slot & 7, kk = k8 ^ (m & 7);
        gA[i] = Abase + (size_t)m*CC + kk*8;
        lA[i] = sA + (i*256 + (tid & ~63)) * 8;
    }
    for (int i = 0; i < 2; ++i){
        int slot = i*256 + tid;
        int m = slot >> 3, k8 = slot & 7, kk = k8 ^ (m & 7);
        gB[i] = Bbase + (size_t)m*CC + kk*8;
        lB[i] = sB + (i*256 + (tid & ~63)) * 8;
    }

    f32x4 acc[4][2] = {};
    for (int kb = 0; kb < 8; ++kb){
        __syncthreads();
        for (int i = 0; i < 4; ++i) gload16(gA[i] + kb*64, lA[i]);
        for (int i = 0; i < 2; ++i) gload16(gB[i] + kb*64, lB[i]);
        __syncthreads();
        for (int ks = 0; ks < 2; ++ks){
            short8 aF[4], bF[2];
            for (int mi = 0; mi < 4; ++mi){
                int m = wr*64 + mi*16 + l15;
                aF[mi] = *(const short8*)&sA[(m*8 + ((ks*4 + quad) ^ (m & 7)))*8];
            }
            for (int ni = 0; ni < 2; ++ni){
                int m = wc*32 + ni*16 + l15;
                bF[ni] = *(const short8*)&sB[(m*8 + ((ks*4 + quad) ^ (m & 7)))*8];
            }
            for (int mi = 0; mi < 4; ++mi)
                for (int ni = 0; ni < 2; ++ni)
                    acc[mi][ni] = __builtin_amdgcn_mfma_f32_16x16x32_bf16(
                        aF[mi], bF[ni], acc[mi][ni], 0, 0, 0);
        }
    }
    float bo[2];
    for (int ni = 0; ni < 2; ++ni) bo[ni] = b_out[co0 + wc*32 + ni*16 + l15];

    __syncthreads();                 // staging done; reuse LDS as fOut[co][t]
    for (int mi = 0; mi < 4; ++mi){
        int tl = wr*64 + mi*16 + quad*4;
        for (int ni = 0; ni < 2; ++ni){
            int cl = wc*32 + ni*16 + l15;
            f32x4 vv;
            for (int r = 0; r < 4; ++r) vv[r] = acc[mi][ni][r] + bo[ni];
            *(f32x4*)&fOut[cl*132 + tl] = vv;
        }
    }
    __syncthreads();
    for (int i = 0; i < 8; ++i){
        int flat = i*256 + tid;
        int co = flat >> 5, ts = (flat & 31)*4;
        f32x4 a = *(const f32x4*)&fOut[co*132 + ts];
        f32x4 mk = *(const f32x4*)(masks + (size_t)n*TT + t0 + ts);
        f32x4 xv = *(const f32x4*)(x + ((size_t)n*CC + co0 + co)*TT + t0 + ts);
        f32x4 o;
        for (int r = 0; r < 4; ++r) o[r] = a[r]*mk[r] + xv[r];
        *(f32x4*)(out + ((size_t)n*CC + co0 + co)*TT + t0 + ts) = o;
    }
}

// ---------------- K4: InstanceNorm over T per (n,c), in place ----------------
__global__ __launch_bounds__(256) void inorm(float* __restrict__ out){
    __shared__ float sS[4], sQ2[4];
    float* row = out + (size_t)blockIdx.x * TT;
    f32x4 vbuf[4];
    float s = 0.f, ss = 0.f;
    for (int i = 0; i < 4; ++i){
        f32x4 vv = *(const f32x4*)(row + (size_t)(i*256 + threadIdx.x)*4);
        vbuf[i] = vv;
        for (int r = 0; r < 4; ++r){ s += vv[r]; ss += vv[r]*vv[r]; }
    }
    for (int d = 1; d < 64; d <<= 1){ s += __shfl_xor(s, d); ss += __shfl_xor(ss, d); }
    int w = threadIdx.x >> 6;
    if ((threadIdx.x & 63) == 0){ sS[w] = s; sQ2[w] = ss; }
    __syncthreads();
    s  = sS[0] + sS[1] + sS[2] + sS[3];
    ss = sQ2[0] + sQ2[1] + sQ2[2] + sQ2[3];
    float mean = s * (1.0f/TT);
    float var  = ss * (1.0f/TT) - mean*mean;
    float rstd = rsqrtf(var + 1e-5f);
    for (int i = 0; i < 4; ++i){
        f32x4 vv = vbuf[i], o;
        for (int r = 0; r < 4; ++r) o[r] = (vv[r] - mean) * rstd;
        *(f32x4*)(row + (size_t)(i*256 + threadIdx.x)*4) = o;
    }
}

extern "C" void kernel_launch(void* const* d_in, const int* in_sizes, int n_in,
                              void* d_out, int out_size, void* d_ws, size_t ws_size,
                              hipStream_t stream) {
    const float* x     = (const float*)d_in[0];
    const float* q     = (const float*)d_in[1];
    const float* k     = (const float*)d_in[2];
    const float* v     = (const float*)d_in[3];
    const float* masks = (const float*)d_in[4];
    const float* W_in  = (const float*)d_in[5];
    const float* b_in  = (const float*)d_in[6];
    const float* W_out = (const float*)d_in[7];
    const float* b_out = (const float*)d_in[8];
    float* out = (float*)d_out;

    ushort* ws  = (ushort*)d_ws;
    ushort* ctx = ws;                           // NTC bf16 (attention output)
    ushort* Wb  = ws + (size_t)NTC;             // 786432
    ushort* Wob = Wb + 786432;                  // 262144
    ushort* P   = Wob + 262144;                 // NB*TT*CQK (Q,K projected)
    ushort* Vt  = P + (size_t)NB*TT*CQK;        // NTC (V projected, transposed)

    wcvt<<<256, 256, 0, stream>>>(W_in, W_out, Wb, Wob);
    proj_gemm<<<1536, 256, 0, stream>>>(q, k, v, Wb, b_in, P, Vt);
    attn_kernel<<<2048, 256, 0, stream>>>(P, Vt, masks, ctx);
    out_gemm<<<1024, 256, 0, stream>>>(ctx, Wob, b_out, x, masks, out);
    inorm<<<2048, 256, 0, stream>>>(out);
}